// Round 7
// baseline (1788.537 us; speedup 1.0000x reference)
//
#include <hip/hip_runtime.h>
#include <math.h>

#define KCODES 1024
#define DIM 64
#define NTOT 131072          // 32*64*64 rows
#define QELEMS 8388608       // 32*64*64*64
#define TAU 1e-3f            // contested-margin threshold (>> fp16-split error bound)
#define WCAP 65536           // worklist capacity

typedef _Float16 half8 __attribute__((ext_vector_type(8)));
typedef float floatx4 __attribute__((ext_vector_type(4)));
typedef float floatx16 __attribute__((ext_vector_type(16)));

// ws layout (4B units):
//   0      counts_i [1024] int     (zeroed)
//   1024   scal [3]: sumsq,nsum,ent; [1027] wcount int (zeroed)
//   1028   (unused) [1024]         (zeroed)
//   2052   dwacc [65536] float     (zeroed; direct atomic accumulation)
//   67588  enorm [1024] float      (holds -0.5*||e||^2)
//   68612  epk [65536 floats = 131072 halves]
//   134148 wlist [65536] int       (contested-pixel worklist; no aliasing)
#define WS_ZERO_FLOATS 67588

__global__ __launch_bounds__(256) void vq_enorm_kernel(const float* __restrict__ embed,
                                                       float* __restrict__ enorm) {
    int k = blockIdx.x * 256 + threadIdx.x;
    if (k < KCODES) {
        const float4* e4 = (const float4*)(embed + (k << 6));
        float s = 0.f;
#pragma unroll
        for (int j = 0; j < 16; ++j) {
            float4 v = e4[j];
            s += v.x * v.x + v.y * v.y + v.z * v.z + v.w * v.w;
        }
        enorm[k] = -0.5f * s;
    }
}

// Pack embed into 32x32x16 MFMA A-fragment layout, fp16 split.
// A[m][k]: m = lane&31, k = (lane>>5)*8 + j (K=16 per chunk, 4 chunks = D 0..63).
// epk8[ct*512 + s*256 + kc*64 + lane], s=0 hi, s=1 lo; ct = 32-code tile.
__global__ __launch_bounds__(256) void vq_epack_kernel(const float* __restrict__ embed,
                                                       _Float16* __restrict__ epk) {
    int tg   = blockIdx.x * 256 + threadIdx.x;   // 0..8191
    int ct   = tg >> 8;
    int kc   = (tg >> 6) & 3;
    int lane = tg & 63;
    int c    = ct * 32 + (lane & 31);
    int d0   = kc * 16 + ((lane >> 5) << 3);
    const float* er = embed + c * 64 + d0;
    float4 f0 = *(const float4*)(er);
    float4 f1 = *(const float4*)(er + 4);
    float va[8] = {f0.x, f0.y, f0.z, f0.w, f1.x, f1.y, f1.z, f1.w};
    half8 h8, l8;
#pragma unroll
    for (int j = 0; j < 8; ++j) {
        _Float16 ah = (_Float16)va[j];
        h8[j] = ah;
        l8[j] = (_Float16)(va[j] - (float)ah);
    }
    half8* o = (half8*)epk;
    int base = ct * 512 + kc * 64 + lane;
    o[base]       = h8;
    o[base + 256] = l8;
}

// MFMA argmin, 32x32x16 tiles: 512 blocks x 512 threads; wave owns 32 pixels.
// x-tile staged in LDS (xsT[d][row], stride 257). dw segment-sums accumulated
// DIRECTLY via L2-resident fp32 atomics in phase 5 (from LDS), eliminating the
// flat_x dump + sort (scatter) + gather (dw) pipeline entirely.
__global__ __launch_bounds__(512, 4) void vq_argmin_mfma(
    const float* __restrict__ in,        // [32][64][64][64] NCHW
    const float* __restrict__ embed,
    const float* __restrict__ enorm,     // -0.5*||e||^2
    const _Float16* __restrict__ epk,
    float* __restrict__ out_quant,
    float* __restrict__ out_idx,
    int*   __restrict__ counts_i,
    float* __restrict__ sumsq,
    float* __restrict__ dwacc,           // [1024][64], zeroed
    int*   __restrict__ wlist,
    int*   __restrict__ wcount)
{
    __shared__ float xs_lds[64 * 257];   // 64.25 KB  x-tile, [d][row] padded
    __shared__ float en_s[KCODES];       // 4 KB  (-0.5*||e||^2)
    __shared__ int   hist[KCODES];       // 4 KB
    __shared__ int   widx[256];          // 1 KB
    __shared__ float wv1[256];           // 1 KB
    __shared__ float xn_s[256];          // 1 KB
    __shared__ float rsum[512];          // 2 KB

    const int t    = threadIdx.x;
    const int blk  = blockIdx.x;         // 0..511 ; block = rows [blk*256, +256)
    const int lane = t & 63;
    const int w    = t >> 6;
    const int hl   = lane >> 5;          // 0/1 half-lane group

    for (int i = t; i < KCODES; i += 512) { en_s[i] = enorm[i]; hist[i] = 0; }

    // phase 1: read in (coalesced 256B instrs) -> xnorm partials + LDS stage
    const int rloc = t & 255;
    const int dhl  = t >> 8;             // 0/1 -> dims [dhl*32, +32)
    const int row0 = (blk << 8) + rloc;
    const int b0 = row0 >> 12, rem0 = row0 & 4095;
    {
        const float* pb = in + b0 * 262144 + (dhl << 5) * 4096 + rem0;
        float xn = 0.f;
#pragma unroll
        for (int d4 = 0; d4 < 8; ++d4) {
            float4 v;
            v.x = pb[(d4 * 4 + 0) * 4096];
            v.y = pb[(d4 * 4 + 1) * 4096];
            v.z = pb[(d4 * 4 + 2) * 4096];
            v.w = pb[(d4 * 4 + 3) * 4096];
            xn += v.x * v.x + v.y * v.y + v.z * v.z + v.w * v.w;
            int dp = (dhl << 5) + (d4 << 2);
            xs_lds[(dp + 0) * 257 + rloc] = v.x;
            xs_lds[(dp + 1) * 257 + rloc] = v.y;
            xs_lds[(dp + 2) * 257 + rloc] = v.z;
            xs_lds[(dp + 3) * 257 + rloc] = v.w;
        }
        rsum[t] = xn;
    }
    __syncthreads();   // xs_lds / en_s / hist / rsum ready
    if (t < 256) xn_s[t] = rsum[t] + rsum[t + 256];   // read by phase 5 (after next barrier)

    // phase 2: B-frags from LDS. B[k][n]: n = lane&31 (pixel), k = hl*8+j.
    half8 xh[4], xl[4];
    {
        int rowl = (w << 5) + (lane & 31);            // block-local row
#pragma unroll
        for (int kc = 0; kc < 4; ++kc) {
#pragma unroll
            for (int j = 0; j < 8; ++j) {
                float xv = xs_lds[(kc * 16 + (hl << 3) + j) * 257 + rowl];
                _Float16 hv = (_Float16)xv;
                xh[kc][j] = hv;
                xl[kc][j] = (_Float16)(xv - (float)hv);
            }
        }
    }

    // phase 3: stream 32 code tiles; track top-2 of acc (maximize) per pixel
    float m1 = -3.4e38f, m2 = -3.4e38f;
    int   ip = 0;                        // packed per-lane id: ct*16 + r

    const half8* epk8 = (const half8*)epk;
    for (int ct = 0; ct < 32; ++ct) {
        const int abase = ct * 512 + lane;
        half8 ah0 = epk8[abase];
        half8 ah1 = epk8[abase + 64];
        half8 ah2 = epk8[abase + 128];
        half8 ah3 = epk8[abase + 192];
        half8 al0 = epk8[abase + 256];
        half8 al1 = epk8[abase + 320];
        half8 al2 = epk8[abase + 384];
        half8 al3 = epk8[abase + 448];
        // C-seed: acc[g*4+i] = en_s[ct*32 + 4*hl + 8*g + i]
        const float* eb = &en_s[ct * 32 + (hl << 2)];
        floatx4 e0 = *(const floatx4*)(eb);
        floatx4 e1 = *(const floatx4*)(eb + 8);
        floatx4 e2 = *(const floatx4*)(eb + 16);
        floatx4 e3 = *(const floatx4*)(eb + 24);
        floatx16 acc;
#pragma unroll
        for (int i = 0; i < 4; ++i) {
            acc[i]      = e0[i];
            acc[4 + i]  = e1[i];
            acc[8 + i]  = e2[i];
            acc[12 + i] = e3[i];
        }
        acc = __builtin_amdgcn_mfma_f32_32x32x16_f16(ah0, xh[0], acc, 0, 0, 0);
        acc = __builtin_amdgcn_mfma_f32_32x32x16_f16(ah1, xh[1], acc, 0, 0, 0);
        acc = __builtin_amdgcn_mfma_f32_32x32x16_f16(ah2, xh[2], acc, 0, 0, 0);
        acc = __builtin_amdgcn_mfma_f32_32x32x16_f16(ah3, xh[3], acc, 0, 0, 0);
        acc = __builtin_amdgcn_mfma_f32_32x32x16_f16(al0, xh[0], acc, 0, 0, 0);
        acc = __builtin_amdgcn_mfma_f32_32x32x16_f16(al1, xh[1], acc, 0, 0, 0);
        acc = __builtin_amdgcn_mfma_f32_32x32x16_f16(al2, xh[2], acc, 0, 0, 0);
        acc = __builtin_amdgcn_mfma_f32_32x32x16_f16(al3, xh[3], acc, 0, 0, 0);
        acc = __builtin_amdgcn_mfma_f32_32x32x16_f16(ah0, xl[0], acc, 0, 0, 0);
        acc = __builtin_amdgcn_mfma_f32_32x32x16_f16(ah1, xl[1], acc, 0, 0, 0);
        acc = __builtin_amdgcn_mfma_f32_32x32x16_f16(ah2, xl[2], acc, 0, 0, 0);
        acc = __builtin_amdgcn_mfma_f32_32x32x16_f16(ah3, xl[3], acc, 0, 0, 0);
        const int kb = ct << 4;
#pragma unroll
        for (int r = 0; r < 16; ++r) {
            float a  = acc[r];
            float tm = fminf(m1, a);              // loser of {m1_old, a}
            m2 = fmaxf(m2, tm);
            if (a > m1) ip = kb + r;              // strict: first hit keeps lowest code
            m1 = fmaxf(m1, a);
        }
    }

    // phase 4: cross-half-lane merge (pixel lives in lanes l and l+32)
    {
        int rr = ip & 15, ct = ip >> 4;
        int ai = ct * 32 + (rr & 3) + ((rr >> 2) << 3) + (hl << 2);   // true code
        float a1v = m1, a2v = m2;
        float o1 = __shfl_xor(a1v, 32, 64);
        int   oi = __shfl_xor(ai, 32, 64);
        float o2 = __shfl_xor(a2v, 32, 64);
        if (o1 > a1v || (o1 == a1v && oi < ai)) {
            a2v = fmaxf(a1v, o2); a1v = o1; ai = oi;
        } else {
            a2v = fmaxf(a2v, o1);
        }
        if (lane < 32) {
            int pl  = (w << 5) + lane;
            int row = (blk << 8) + pl;
            widx[pl] = ai;
            wv1[pl]  = -2.0f * a1v;                   // = dv_min
            out_idx[row] = (float)ai;
            atomicAdd(&hist[ai], 1);
            if (2.0f * (a1v - a2v) < TAU) {           // dv2 - dv1 < TAU
                int pos = atomicAdd(wcount, 1);
                if (pos < WCAP) wlist[pos] = row;
            }
        }
    }
    __syncthreads();

    // phase 5: hist flush + quant write + dw atomics + sumsq
    for (int i = t; i < KCODES; i += 512) {
        int v = hist[i];
        if (v) atomicAdd(&counts_i[i], v);
    }
    {
        int k = widx[rloc];
        const float4* eq = (const float4*)(embed + (k << 6) + (dhl << 5));
        float* ob = out_quant + b0 * 262144 + (dhl << 5) * 4096 + rem0;
#pragma unroll
        for (int d4 = 0; d4 < 8; ++d4) {
            float4 e4v = eq[d4];
            ob[(d4 * 4 + 0) * 4096] = e4v.x;
            ob[(d4 * 4 + 1) * 4096] = e4v.y;
            ob[(d4 * 4 + 2) * 4096] = e4v.z;
            ob[(d4 * 4 + 3) * 4096] = e4v.w;
        }
        // dw: this thread owns (pixel rloc, dims [dhl*32, +32)); dwacc is
        // L2-resident (256 KB) -> scatter atomics, ~128 adds/slot average.
        float* dst = dwacc + (k << 6) + (dhl << 5);
#pragma unroll
        for (int d = 0; d < 32; ++d)
            atomicAdd(&dst[d], xs_lds[((dhl << 5) + d) * 257 + rloc]);
        rsum[t] = (t < 256) ? (wv1[t] + xn_s[t]) : 0.f;
    }
    __syncthreads();
    for (int s = 256; s > 0; s >>= 1) {
        if (t < s) rsum[t] += rsum[t + s];
        __syncthreads();
    }
    if (t == 0) atomicAdd(sumsq, rsum[0]);
}

// Exact double-precision refine of contested pixels; patches idx, quant,
// counts, loss AND dwacc (move x from old code row to new code row).
__global__ __launch_bounds__(256) void vq_refine_kernel(
    const float* __restrict__ embed,
    const float* __restrict__ in,
    float* __restrict__ out_idx,
    float* __restrict__ out_quant,
    int*   __restrict__ counts_i,
    float* __restrict__ scal,            // [0]=sumsq
    float* __restrict__ dwacc,
    int*   __restrict__ wlist,
    const int* __restrict__ wcount)
{
    const int lane = threadIdx.x & 63;
    const int gw   = (blockIdx.x << 2) + (threadIdx.x >> 6);
    const int nw   = gridDim.x << 2;
    int count = *wcount;
    if (count > WCAP) count = WCAP;

    for (int e = gw; e < count; e += nw) {
        int r = wlist[e];
        int b = r >> 12, rem = r & 4095;
        float4 xr[16];
#pragma unroll
        for (int qq = 0; qq < 16; ++qq) {
            xr[qq].x = in[b * 262144 + (qq * 4 + 0) * 4096 + rem];
            xr[qq].y = in[b * 262144 + (qq * 4 + 1) * 4096 + rem];
            xr[qq].z = in[b * 262144 + (qq * 4 + 2) * 4096 + rem];
            xr[qq].w = in[b * 262144 + (qq * 4 + 3) * 4096 + rem];
        }
        double bv = 1e300;
        int    bi = 0;
        for (int j = 0; j < 16; ++j) {
            int c = (j << 6) + lane;
            const float4* er = (const float4*)(embed + (c << 6));
            double acc = 0.0;
#pragma unroll
            for (int qq = 0; qq < 16; ++qq) {
                float4 ev = er[qq];
                double d0 = (double)xr[qq].x - (double)ev.x;
                double d1 = (double)xr[qq].y - (double)ev.y;
                double d2 = (double)xr[qq].z - (double)ev.z;
                double d3 = (double)xr[qq].w - (double)ev.w;
                acc += d0 * d0 + d1 * d1 + d2 * d2 + d3 * d3;
            }
            if (acc < bv) { bv = acc; bi = c; }
        }
#pragma unroll
        for (int off = 1; off < 64; off <<= 1) {
            double ov = __shfl_xor(bv, off, 64);
            int    oi = __shfl_xor(bi, off, 64);
            if (ov < bv || (ov == bv && oi < bi)) { bv = ov; bi = oi; }
        }
        int oldi = (int)out_idx[r];
        if (bi != oldi) {
            float xd  = in[b * 262144 + lane * 4096 + rem];
            float en_ = embed[(bi << 6) + lane];
            float eo_ = embed[(oldi << 6) + lane];
            out_quant[b * 262144 + lane * 4096 + rem] = en_;
            atomicAdd(&dwacc[(bi << 6) + lane], xd);      // move x: old -> new
            atomicAdd(&dwacc[(oldi << 6) + lane], -xd);
            float dl = (en_ - xd) * (en_ - xd) - (eo_ - xd) * (eo_ - xd);
#pragma unroll
            for (int off = 1; off < 64; off <<= 1) dl += __shfl_xor(dl, off, 64);
            if (lane == 0) {
                out_idx[r] = (float)bi;
                atomicAdd(&scal[0], dl);
                atomicSub(&counts_i[oldi], 1);
                atomicAdd(&counts_i[bi], 1);
            }
        }
    }
}

__global__ __launch_bounds__(256) void vq_fin_a_kernel(
    const float* __restrict__ ema_cs,
    const int*   __restrict__ counts_i,
    float* __restrict__ scal,
    float* __restrict__ out)
{
    __shared__ float r1[256], r2[256];
    const int t = threadIdx.x;
    const int k = blockIdx.x * 256 + t;
    float* o_ncs = out + QELEMS + 2 + NTOT;

    float c   = (float)counts_i[k];
    float ncs = 0.99f * ema_cs[k] + 0.01f * c;
    o_ncs[k] = ncs;
    float p = c / (float)NTOT;
    r1[t] = ncs;
    r2[t] = p * logf(p + 1e-10f);
    __syncthreads();
    for (int s = 128; s > 0; s >>= 1) {
        if (t < s) { r1[t] += r1[t + s]; r2[t] += r2[t + s]; }
        __syncthreads();
    }
    if (t == 0) {
        atomicAdd(&scal[1], r1[0]);
        atomicAdd(&scal[2], r2[0]);
    }
}

__global__ __launch_bounds__(256) void vq_fin_b_kernel(
    const float* __restrict__ ema_cs,
    const float* __restrict__ ema_w,
    const int*   __restrict__ counts_i,
    const float* __restrict__ dwacc,
    const float* __restrict__ scal,
    float* __restrict__ out)
{
    const int t = threadIdx.x;
    float* o_loss  = out + QELEMS;
    float* o_perp  = out + QELEMS + 1;
    float* o_ncs   = out + QELEMS + 2 + NTOT;
    float* o_emaw  = o_ncs + KCODES;
    float* o_embed = o_emaw + KCODES * DIM;

    float n = scal[1];
    float denom = n + (float)KCODES * 1e-5f;
#pragma unroll
    for (int u = 0; u < 8; ++u) {
        int i = (blockIdx.x << 11) + (u << 8) + t;
        int k = i >> 6;
        float c   = (float)counts_i[k];
        float ncs = 0.99f * ema_cs[k] + 0.01f * c;
        float cs  = (ncs + 1e-5f) / denom * n;
        cs = fmaxf(cs, 1e-5f);
        float w = 0.99f * ema_w[i] + 0.01f * dwacc[i];
        o_emaw[i]  = w;
        o_embed[i] = w / cs;
    }
    if (blockIdx.x == 0 && t == 0) {
        o_loss[0] = 0.25f * scal[0] / (float)QELEMS;
        o_perp[0] = expf(-scal[2]);
    }
}

extern "C" void kernel_launch(void* const* d_in, const int* in_sizes, int n_in,
                              void* d_out, int out_size, void* d_ws, size_t ws_size,
                              hipStream_t stream) {
    const float* in     = (const float*)d_in[0];
    const float* embed  = (const float*)d_in[1];
    const float* ema_cs = (const float*)d_in[2];
    const float* ema_w  = (const float*)d_in[3];
    float* out = (float*)d_out;
    float* ws  = (float*)d_ws;

    int*   counts_i = (int*)ws;              // 1024
    float* scal     = ws + 1024;             // 3 + wcount at 1027
    int*   wcount   = (int*)ws + 1027;
    float* dwacc    = ws + 2052;             // 65536
    float* enorm    = ws + 67588;            // 1024
    _Float16* epk   = (_Float16*)(ws + 68612);   // 131072 halves
    int*   wlist    = (int*)ws + 134148;     // 65536 (no aliasing)
    float* o_idx    = out + QELEMS + 2;

    hipMemsetAsync(d_ws, 0, (size_t)WS_ZERO_FLOATS * sizeof(float), stream);
    vq_enorm_kernel<<<4, 256, 0, stream>>>(embed, enorm);
    vq_epack_kernel<<<32, 256, 0, stream>>>(embed, epk);
    vq_argmin_mfma<<<512, 512, 0, stream>>>(in, embed, enorm, epk, out, o_idx,
                                            counts_i, scal, dwacc, wlist, wcount);
    vq_refine_kernel<<<128, 256, 0, stream>>>(embed, in, o_idx, out,
                                              counts_i, scal, dwacc, wlist, wcount);
    vq_fin_a_kernel<<<4, 256, 0, stream>>>(ema_cs, counts_i, scal, out);
    vq_fin_b_kernel<<<32, 256, 0, stream>>>(ema_cs, ema_w, counts_i, dwacc, scal, out);
}

// Round 8
// 246.560 us; speedup vs baseline: 7.2540x; 7.2540x over previous
//
#include <hip/hip_runtime.h>
#include <math.h>

#define KCODES 1024
#define DIM 64
#define NTOT 131072          // 32*64*64 rows
#define QELEMS 8388608       // 32*64*64*64
#define TAU 1e-3f            // contested-margin threshold (>> fp16-split error bound)
#define WCAP 65536           // worklist capacity (aliases dwacc region)

typedef _Float16 half8 __attribute__((ext_vector_type(8)));
typedef float floatx4 __attribute__((ext_vector_type(4)));
typedef float floatx16 __attribute__((ext_vector_type(16)));

// ws layout (4B units):
//   0      counts_i [1024] int     (zeroed)
//   1024   scal [3]: sumsq,nsum,ent; [1027] wcount int (zeroed)
//   1028   cursor [1024] int       (zeroed)
//   2052   dwacc [65536] float     (zeroed; doubles as refine worklist, re-zeroed)
//   67588  enorm [1024] float      (holds -0.5*||e||^2)
//   68612  epk [65536 floats = 131072 halves]   (argmin phase)
//   68612  keys [131072] int                    (tail phase, aliases epk)
//   199684 flat_x [8388608] float  (optional)
#define WS_ZERO_FLOATS 67588
#define WS_FLAT_OFF 199684
#define WS_NEED_FLAT ((size_t)(WS_FLAT_OFF + QELEMS) * 4)

// Pack embed into 32x32x16 MFMA A-fragment layout (fp16 split) AND compute
// enorm[k] = -0.5*||e_k||^2 via LDS partial reduction (fused, one launch).
// A[m][k]: m = lane&31, k = (lane>>5)*8 + j. Block = one 32-code tile ct.
// epk8[ct*512 + s*256 + kc*64 + lane], s=0 hi, s=1 lo.
__global__ __launch_bounds__(256) void vq_epack_kernel(const float* __restrict__ embed,
                                                       _Float16* __restrict__ epk,
                                                       float* __restrict__ enorm) {
    __shared__ float sp[256];
    const int tid  = threadIdx.x;
    const int ct   = blockIdx.x;                 // 0..31
    const int kc   = (tid >> 6) & 3;
    const int lane = tid & 63;
    const int c    = ct * 32 + (lane & 31);
    const int d0   = kc * 16 + ((lane >> 5) << 3);
    const float* er = embed + c * 64 + d0;
    float4 f0 = *(const float4*)(er);
    float4 f1 = *(const float4*)(er + 4);
    float va[8] = {f0.x, f0.y, f0.z, f0.w, f1.x, f1.y, f1.z, f1.w};
    half8 h8, l8;
    float s = 0.f;
#pragma unroll
    for (int j = 0; j < 8; ++j) {
        s += va[j] * va[j];
        _Float16 ah = (_Float16)va[j];
        h8[j] = ah;
        l8[j] = (_Float16)(va[j] - (float)ah);
    }
    half8* o = (half8*)epk;
    int base = ct * 512 + kc * 64 + lane;
    o[base]       = h8;
    o[base + 256] = l8;
    sp[tid] = s;
    __syncthreads();
    if (tid < 32) {
        float tsum = 0.f;
#pragma unroll
        for (int k = 0; k < 8; ++k) tsum += sp[tid + k * 32];
        enorm[ct * 32 + tid] = -0.5f * tsum;
    }
}

// MFMA argmin, 32x32x16 tiles (frozen from R6: 252.6us config): 512 blocks x
// 512 threads; wave owns 32 pixels; x-tile staged in LDS (xsT[d][row], pad 257)
// -> full-line coalesced flat_x dump (kills HBM write amplification) and
// LDS-sourced B-frags. flat stores drain under the tile loop (no barrier).
__global__ __launch_bounds__(512, 4) void vq_argmin_mfma(
    const float* __restrict__ in,        // [32][64][64][64] NCHW
    const float* __restrict__ embed,
    const float* __restrict__ enorm,     // -0.5*||e||^2
    const _Float16* __restrict__ epk,
    float* __restrict__ out_quant,
    float* __restrict__ out_idx,
    int*   __restrict__ counts_i,
    float* __restrict__ sumsq,
    float* __restrict__ flat_x,          // or nullptr
    int*   __restrict__ wlist,
    int*   __restrict__ wcount)
{
    __shared__ float xs_lds[64 * 257];   // 64.25 KB  x-tile, [d][row] padded
    __shared__ float en_s[KCODES];       // 4 KB  (-0.5*||e||^2)
    __shared__ int   hist[KCODES];       // 4 KB
    __shared__ int   widx[256];          // 1 KB
    __shared__ float wv1[256];           // 1 KB
    __shared__ float xn_s[256];          // 1 KB
    __shared__ float rsum[512];          // 2 KB

    const int t    = threadIdx.x;
    const int blk  = blockIdx.x;         // 0..511 ; block = rows [blk*256, +256)
    const int lane = t & 63;
    const int w    = t >> 6;
    const int hl   = lane >> 5;          // 0/1 half-lane group

    for (int i = t; i < KCODES; i += 512) { en_s[i] = enorm[i]; hist[i] = 0; }

    // phase 1: read in (coalesced 256B instrs) -> xnorm partials + LDS stage
    const int rloc = t & 255;
    const int dhl  = t >> 8;             // 0/1 -> dims [dhl*32, +32)
    const int row0 = (blk << 8) + rloc;
    const int b0 = row0 >> 12, rem0 = row0 & 4095;
    {
        const float* pb = in + b0 * 262144 + (dhl << 5) * 4096 + rem0;
        float xn = 0.f;
#pragma unroll
        for (int d4 = 0; d4 < 8; ++d4) {
            float4 v;
            v.x = pb[(d4 * 4 + 0) * 4096];
            v.y = pb[(d4 * 4 + 1) * 4096];
            v.z = pb[(d4 * 4 + 2) * 4096];
            v.w = pb[(d4 * 4 + 3) * 4096];
            xn += v.x * v.x + v.y * v.y + v.z * v.z + v.w * v.w;
            int dp = (dhl << 5) + (d4 << 2);
            xs_lds[(dp + 0) * 257 + rloc] = v.x;
            xs_lds[(dp + 1) * 257 + rloc] = v.y;
            xs_lds[(dp + 2) * 257 + rloc] = v.z;
            xs_lds[(dp + 3) * 257 + rloc] = v.w;
        }
        rsum[t] = xn;
    }
    __syncthreads();   // xs_lds / en_s / hist / rsum ready
    if (t < 256) xn_s[t] = rsum[t] + rsum[t + 256];   // read by phase 5 (after next barrier)

    // phase 2a: B-frags from LDS. B[k][n]: n = lane&31 (pixel), k = hl*8+j.
    half8 xh[4], xl[4];
    {
        int rowl = (w << 5) + (lane & 31);            // block-local row
#pragma unroll
        for (int kc = 0; kc < 4; ++kc) {
#pragma unroll
            for (int j = 0; j < 8; ++j) {
                float xv = xs_lds[(kc * 16 + (hl << 3) + j) * 257 + rowl];
                _Float16 hv = (_Float16)xv;
                xh[kc][j] = hv;
                xl[kc][j] = (_Float16)(xv - (float)hv);
            }
        }
    }

    // phase 2b: flat_x dump, full-line coalesced (1 KB contiguous per instr).
    // No barrier after: stores drain under the tile loop.
    if (flat_x) {
        const int ch   = lane & 15;
        const int rsub = lane >> 4;
#pragma unroll
        for (int i = 0; i < 8; ++i) {
            int rowl = (w << 5) + (i << 2) + rsub;
            float4 v;
            v.x = xs_lds[(ch * 4 + 0) * 257 + rowl];
            v.y = xs_lds[(ch * 4 + 1) * 257 + rowl];
            v.z = xs_lds[(ch * 4 + 2) * 257 + rowl];
            v.w = xs_lds[(ch * 4 + 3) * 257 + rowl];
            *(float4*)(flat_x + (((size_t)((blk << 8) + rowl)) << 6) + (ch << 2)) = v;
        }
    }

    // phase 3: stream 32 code tiles; track top-2 of acc (maximize) per pixel
    float m1 = -3.4e38f, m2 = -3.4e38f;
    int   ip = 0;                        // packed per-lane id: ct*16 + r

    const half8* epk8 = (const half8*)epk;
    for (int ct = 0; ct < 32; ++ct) {
        const int abase = ct * 512 + lane;
        half8 ah0 = epk8[abase];
        half8 ah1 = epk8[abase + 64];
        half8 ah2 = epk8[abase + 128];
        half8 ah3 = epk8[abase + 192];
        half8 al0 = epk8[abase + 256];
        half8 al1 = epk8[abase + 320];
        half8 al2 = epk8[abase + 384];
        half8 al3 = epk8[abase + 448];
        // C-seed: acc[g*4+i] = en_s[ct*32 + 4*hl + 8*g + i]
        const float* eb = &en_s[ct * 32 + (hl << 2)];
        floatx4 e0 = *(const floatx4*)(eb);
        floatx4 e1 = *(const floatx4*)(eb + 8);
        floatx4 e2 = *(const floatx4*)(eb + 16);
        floatx4 e3 = *(const floatx4*)(eb + 24);
        floatx16 acc;
#pragma unroll
        for (int i = 0; i < 4; ++i) {
            acc[i]      = e0[i];
            acc[4 + i]  = e1[i];
            acc[8 + i]  = e2[i];
            acc[12 + i] = e3[i];
        }
        acc = __builtin_amdgcn_mfma_f32_32x32x16_f16(ah0, xh[0], acc, 0, 0, 0);
        acc = __builtin_amdgcn_mfma_f32_32x32x16_f16(ah1, xh[1], acc, 0, 0, 0);
        acc = __builtin_amdgcn_mfma_f32_32x32x16_f16(ah2, xh[2], acc, 0, 0, 0);
        acc = __builtin_amdgcn_mfma_f32_32x32x16_f16(ah3, xh[3], acc, 0, 0, 0);
        acc = __builtin_amdgcn_mfma_f32_32x32x16_f16(al0, xh[0], acc, 0, 0, 0);
        acc = __builtin_amdgcn_mfma_f32_32x32x16_f16(al1, xh[1], acc, 0, 0, 0);
        acc = __builtin_amdgcn_mfma_f32_32x32x16_f16(al2, xh[2], acc, 0, 0, 0);
        acc = __builtin_amdgcn_mfma_f32_32x32x16_f16(al3, xh[3], acc, 0, 0, 0);
        acc = __builtin_amdgcn_mfma_f32_32x32x16_f16(ah0, xl[0], acc, 0, 0, 0);
        acc = __builtin_amdgcn_mfma_f32_32x32x16_f16(ah1, xl[1], acc, 0, 0, 0);
        acc = __builtin_amdgcn_mfma_f32_32x32x16_f16(ah2, xl[2], acc, 0, 0, 0);
        acc = __builtin_amdgcn_mfma_f32_32x32x16_f16(ah3, xl[3], acc, 0, 0, 0);
        const int kb = ct << 4;
#pragma unroll
        for (int r = 0; r < 16; ++r) {
            float a  = acc[r];
            float tm = fminf(m1, a);              // loser of {m1_old, a}
            m2 = fmaxf(m2, tm);
            if (a > m1) ip = kb + r;              // strict: first hit keeps lowest code
            m1 = fmaxf(m1, a);
        }
    }

    // phase 4: cross-half-lane merge (pixel lives in lanes l and l+32)
    {
        int rr = ip & 15, ct = ip >> 4;
        int ai = ct * 32 + (rr & 3) + ((rr >> 2) << 3) + (hl << 2);   // true code
        float a1v = m1, a2v = m2;
        float o1 = __shfl_xor(a1v, 32, 64);
        int   oi = __shfl_xor(ai, 32, 64);
        float o2 = __shfl_xor(a2v, 32, 64);
        if (o1 > a1v || (o1 == a1v && oi < ai)) {
            a2v = fmaxf(a1v, o2); a1v = o1; ai = oi;
        } else {
            a2v = fmaxf(a2v, o1);
        }
        if (lane < 32) {
            int pl  = (w << 5) + lane;
            int row = (blk << 8) + pl;
            widx[pl] = ai;
            wv1[pl]  = -2.0f * a1v;                   // = dv_min
            out_idx[row] = (float)ai;
            atomicAdd(&hist[ai], 1);
            if (2.0f * (a1v - a2v) < TAU) {           // dv2 - dv1 < TAU
                int pos = atomicAdd(wcount, 1);
                if (pos < WCAP) wlist[pos] = row;
            }
        }
    }
    __syncthreads();

    // phase 5: hist flush + quant write + sumsq (dv_min + |x|^2)
    for (int i = t; i < KCODES; i += 512) {
        int v = hist[i];
        if (v) atomicAdd(&counts_i[i], v);
    }
    {
        int k = widx[rloc];
        const float4* eq = (const float4*)(embed + (k << 6) + (dhl << 5));
        float* ob = out_quant + b0 * 262144 + (dhl << 5) * 4096 + rem0;
#pragma unroll
        for (int d4 = 0; d4 < 8; ++d4) {
            float4 e4v = eq[d4];
            ob[(d4 * 4 + 0) * 4096] = e4v.x;
            ob[(d4 * 4 + 1) * 4096] = e4v.y;
            ob[(d4 * 4 + 2) * 4096] = e4v.z;
            ob[(d4 * 4 + 3) * 4096] = e4v.w;
        }
        rsum[t] = (t < 256) ? (wv1[t] + xn_s[t]) : 0.f;
    }
    __syncthreads();
    for (int s = 256; s > 0; s >>= 1) {
        if (t < s) rsum[t] += rsum[t + s];
        __syncthreads();
    }
    if (t == 0) atomicAdd(sumsq, rsum[0]);
}

// Refine of contested pixels, fp32 direct distances (error ~1e-5 << TAU=1e-3;
// reference itself is fp32). Patches idx/quant/counts/loss; restores wlist=0.
__global__ __launch_bounds__(256) void vq_refine_kernel(
    const float* __restrict__ embed,
    const float* __restrict__ in,
    const float* __restrict__ flat_x,    // may be null
    float* __restrict__ out_idx,
    float* __restrict__ out_quant,
    int*   __restrict__ counts_i,
    float* __restrict__ scal,            // [0]=sumsq
    int*   __restrict__ wlist,
    const int* __restrict__ wcount)
{
    const int lane = threadIdx.x & 63;
    const int gw   = (blockIdx.x << 2) + (threadIdx.x >> 6);
    const int nw   = gridDim.x << 2;
    int count = *wcount;
    if (count > WCAP) count = WCAP;

    for (int e = gw; e < count; e += nw) {
        int r = wlist[e];
        int b = r >> 12, rem = r & 4095;
        float4 xr[16];
        if (flat_x) {
            const float4* xs4 = (const float4*)(flat_x + ((size_t)r << 6));
#pragma unroll
            for (int qq = 0; qq < 16; ++qq) xr[qq] = xs4[qq];
        } else {
#pragma unroll
            for (int qq = 0; qq < 16; ++qq) {
                xr[qq].x = in[b * 262144 + (qq * 4 + 0) * 4096 + rem];
                xr[qq].y = in[b * 262144 + (qq * 4 + 1) * 4096 + rem];
                xr[qq].z = in[b * 262144 + (qq * 4 + 2) * 4096 + rem];
                xr[qq].w = in[b * 262144 + (qq * 4 + 3) * 4096 + rem];
            }
        }
        float bv = 3.4e38f;
        int   bi = 0;
        for (int j = 0; j < 16; ++j) {
            int c = (j << 6) + lane;
            const float4* er = (const float4*)(embed + (c << 6));
            float acc = 0.f;
#pragma unroll
            for (int qq = 0; qq < 16; ++qq) {
                float4 ev = er[qq];
                float d0 = xr[qq].x - ev.x;
                float d1 = xr[qq].y - ev.y;
                float d2 = xr[qq].z - ev.z;
                float d3 = xr[qq].w - ev.w;
                acc += d0 * d0 + d1 * d1 + d2 * d2 + d3 * d3;
            }
            if (acc < bv) { bv = acc; bi = c; }
        }
#pragma unroll
        for (int off = 1; off < 64; off <<= 1) {
            float ov = __shfl_xor(bv, off, 64);
            int   oi = __shfl_xor(bi, off, 64);
            if (ov < bv || (ov == bv && oi < bi)) { bv = ov; bi = oi; }
        }
        int oldi = (int)out_idx[r];
        if (bi != oldi) {
            float xd = flat_x ? flat_x[((size_t)r << 6) + lane]
                              : in[b * 262144 + lane * 4096 + rem];
            float en_ = embed[(bi << 6) + lane];
            float eo_ = embed[(oldi << 6) + lane];
            out_quant[b * 262144 + lane * 4096 + rem] = en_;
            float dl = (en_ - xd) * (en_ - xd) - (eo_ - xd) * (eo_ - xd);
#pragma unroll
            for (int off = 1; off < 64; off <<= 1) dl += __shfl_xor(dl, off, 64);
            if (lane == 0) {
                out_idx[r] = (float)bi;
                atomicAdd(&scal[0], dl);
                atomicSub(&counts_i[oldi], 1);
                atomicAdd(&counts_i[bi], 1);
            }
        }
        if (lane == 0) wlist[e] = 0;   // restore dwacc zero
    }
}

// ---- tail (frozen) ----
__global__ __launch_bounds__(256) void vq_scatter_kernel(
    const float* __restrict__ idxf,
    const int*   __restrict__ counts_i,
    int* __restrict__ cursor,
    int* __restrict__ keys)
{
    __shared__ int lstarts[KCODES];
    __shared__ int lh[KCODES];
    __shared__ int part[256];
    const int t   = threadIdx.x;
    const int blk = blockIdx.x;

    int4 c4 = *(const int4*)(counts_i + (t << 2));
    part[t] = c4.x + c4.y + c4.z + c4.w;
    {
        int tb = t << 2;
        lh[tb] = 0; lh[tb + 1] = 0; lh[tb + 2] = 0; lh[tb + 3] = 0;
    }
    __syncthreads();
    for (int off = 1; off < 256; off <<= 1) {
        int v   = part[t];
        int add = (t >= off) ? part[t - off] : 0;
        __syncthreads();
        part[t] = v + add;
        __syncthreads();
    }
    {
        int base = (t == 0) ? 0 : part[t - 1];
        int tb = t << 2;
        lstarts[tb]     = base;
        lstarts[tb + 1] = base + c4.x;
        lstarts[tb + 2] = base + c4.x + c4.y;
        lstarts[tb + 3] = base + c4.x + c4.y + c4.z;
    }
    __syncthreads();

    const int i0 = (blk << 9) + t;
    const int i1 = i0 + 256;
    int code0 = (int)idxf[i0];
    int rank0 = atomicAdd(&lh[code0], 1);
    int code1 = (int)idxf[i1];
    int rank1 = atomicAdd(&lh[code1], 1);
    __syncthreads();
    for (int k = t; k < KCODES; k += 256) {
        int cnt = lh[k];
        if (cnt) lh[k] = lstarts[k] + atomicAdd(&cursor[k], cnt);
    }
    __syncthreads();
    keys[lh[code0] + rank0] = (code0 << 17) | i0;
    keys[lh[code1] + rank1] = (code1 << 17) | i1;
}

__global__ __launch_bounds__(256) void vq_dw_kernel(
    const float* __restrict__ flat_x,
    const int*   __restrict__ keys,
    float* __restrict__ dwacc)
{
    const int t   = threadIdx.x;
    const int blk = blockIdx.x;
    const int wv  = t >> 6, d = t & 63;
    const int base = (blk << 9) + (wv << 7);

    int key   = keys[base];
    int c_cur = key >> 17;
    int r     = key & 0x1FFFF;
    float acc = 0.f;
#pragma unroll 4
    for (int m = 0; m < 128; ++m) {
        float x = flat_x[((size_t)r << 6) + d];
        int nkey = (m < 127) ? keys[base + m + 1] : -1;
        int c_n  = nkey >> 17;
        int r_n  = nkey & 0x1FFFF;
        acc += x;
        if (c_n != c_cur) {
            atomicAdd(&dwacc[(c_cur << 6) + d], acc);
            acc = 0.f;
            c_cur = c_n;
        }
        r = r_n;
    }
}

__global__ __launch_bounds__(256) void vq_dw_nchw_kernel(
    const float* __restrict__ in,
    const int*   __restrict__ keys,
    float* __restrict__ dwacc)
{
    const int t   = threadIdx.x;
    const int blk = blockIdx.x;
    const int wv  = t >> 6, d = t & 63;
    const int base = (blk << 9) + (wv << 7);

    int key   = keys[base];
    int c_cur = key >> 17;
    int r     = key & 0x1FFFF;
    float acc = 0.f;
    for (int m = 0; m < 128; ++m) {
        int b = r >> 12, rem = r & 4095;
        float x = in[b * 262144 + d * 4096 + rem];
        int nkey = (m < 127) ? keys[base + m + 1] : -1;
        int c_n  = nkey >> 17;
        int r_n  = nkey & 0x1FFFF;
        acc += x;
        if (c_n != c_cur) {
            atomicAdd(&dwacc[(c_cur << 6) + d], acc);
            acc = 0.f;
            c_cur = c_n;
        }
        r = r_n;
    }
}

__global__ __launch_bounds__(256) void vq_fin_a_kernel(
    const float* __restrict__ ema_cs,
    const int*   __restrict__ counts_i,
    float* __restrict__ scal,
    float* __restrict__ out)
{
    __shared__ float r1[256], r2[256];
    const int t = threadIdx.x;
    const int k = blockIdx.x * 256 + t;
    float* o_ncs = out + QELEMS + 2 + NTOT;

    float c   = (float)counts_i[k];
    float ncs = 0.99f * ema_cs[k] + 0.01f * c;
    o_ncs[k] = ncs;
    float p = c / (float)NTOT;
    r1[t] = ncs;
    r2[t] = p * logf(p + 1e-10f);
    __syncthreads();
    for (int s = 128; s > 0; s >>= 1) {
        if (t < s) { r1[t] += r1[t + s]; r2[t] += r2[t + s]; }
        __syncthreads();
    }
    if (t == 0) {
        atomicAdd(&scal[1], r1[0]);
        atomicAdd(&scal[2], r2[0]);
    }
}

__global__ __launch_bounds__(256) void vq_fin_b_kernel(
    const float* __restrict__ ema_cs,
    const float* __restrict__ ema_w,
    const int*   __restrict__ counts_i,
    const float* __restrict__ dwacc,
    const float* __restrict__ scal,
    float* __restrict__ out)
{
    const int t = threadIdx.x;
    float* o_loss  = out + QELEMS;
    float* o_perp  = out + QELEMS + 1;
    float* o_ncs   = out + QELEMS + 2 + NTOT;
    float* o_emaw  = o_ncs + KCODES;
    float* o_embed = o_emaw + KCODES * DIM;

    float n = scal[1];
    float denom = n + (float)KCODES * 1e-5f;
#pragma unroll
    for (int u = 0; u < 8; ++u) {
        int i = (blockIdx.x << 11) + (u << 8) + t;
        int k = i >> 6;
        float c   = (float)counts_i[k];
        float ncs = 0.99f * ema_cs[k] + 0.01f * c;
        float cs  = (ncs + 1e-5f) / denom * n;
        cs = fmaxf(cs, 1e-5f);
        float w = 0.99f * ema_w[i] + 0.01f * dwacc[i];
        o_emaw[i]  = w;
        o_embed[i] = w / cs;
    }
    if (blockIdx.x == 0 && t == 0) {
        o_loss[0] = 0.25f * scal[0] / (float)QELEMS;
        o_perp[0] = expf(-scal[2]);
    }
}

extern "C" void kernel_launch(void* const* d_in, const int* in_sizes, int n_in,
                              void* d_out, int out_size, void* d_ws, size_t ws_size,
                              hipStream_t stream) {
    const float* in     = (const float*)d_in[0];
    const float* embed  = (const float*)d_in[1];
    const float* ema_cs = (const float*)d_in[2];
    const float* ema_w  = (const float*)d_in[3];
    float* out = (float*)d_out;
    float* ws  = (float*)d_ws;

    int*   counts_i = (int*)ws;              // 1024
    float* scal     = ws + 1024;             // 3 + wcount at 1027
    int*   wcount   = (int*)ws + 1027;
    int*   cursor   = (int*)ws + 1028;       // 1024
    float* dwacc    = ws + 2052;             // 65536 (worklist alias)
    int*   wlist    = (int*)ws + 2052;
    float* enorm    = ws + 67588;            // 1024
    _Float16* epk   = (_Float16*)(ws + 68612);   // 131072 halves (argmin phase)
    int*   keys     = (int*)ws + 68612;      // tail phase, aliases epk
    const bool use_flat = ws_size >= WS_NEED_FLAT;
    float* flat_x   = use_flat ? (ws + WS_FLAT_OFF) : (float*)0;
    float* o_idx    = out + QELEMS + 2;

    hipMemsetAsync(d_ws, 0, (size_t)WS_ZERO_FLOATS * sizeof(float), stream);
    vq_epack_kernel<<<32, 256, 0, stream>>>(embed, epk, enorm);
    vq_argmin_mfma<<<512, 512, 0, stream>>>(in, embed, enorm, epk, out, o_idx,
                                            counts_i, scal, flat_x, wlist, wcount);
    vq_refine_kernel<<<128, 256, 0, stream>>>(embed, in, flat_x, o_idx, out,
                                              counts_i, scal, wlist, wcount);
    vq_scatter_kernel<<<256, 256, 0, stream>>>(o_idx, counts_i, cursor, keys);
    if (use_flat)
        vq_dw_kernel<<<256, 256, 0, stream>>>(flat_x, keys, dwacc);
    else
        vq_dw_nchw_kernel<<<256, 256, 0, stream>>>(in, keys, dwacc);
    vq_fin_a_kernel<<<4, 256, 0, stream>>>(ema_cs, counts_i, scal, out);
    vq_fin_b_kernel<<<32, 256, 0, stream>>>(ema_cs, ema_w, counts_i, dwacc, scal, out);
}

// Round 9
// 246.419 us; speedup vs baseline: 7.2581x; 1.0006x over previous
//
#include <hip/hip_runtime.h>
#include <math.h>

#define KCODES 1024
#define DIM 64
#define NTOT 131072          // 32*64*64 rows
#define QELEMS 8388608       // 32*64*64*64
#define TAU 1e-3f            // contested-margin threshold (>> fp16-split error bound)
#define WCAP 65536           // worklist capacity (aliases dwacc region)

typedef _Float16 half8 __attribute__((ext_vector_type(8)));
typedef float floatx4 __attribute__((ext_vector_type(4)));
typedef float floatx16 __attribute__((ext_vector_type(16)));

// ws layout (4B units):
//   0      counts_i [1024] int     (zeroed by epack)
//   1024   scal [3]: sumsq,nsum,ent; [1027] wcount int (zeroed by epack)
//   1028   cursor [1024] int       (zeroed by epack)
//   2052   dwacc [65536] float     (zeroed by epack; aliases refine worklist, re-zeroed)
//   67588  enorm [1024] float      (holds -0.5*||e||^2)
//   68612  epk [65536 floats = 131072 halves]   (argmin phase)
//   68612  keys [131072] int                    (tail phase, aliases epk)
//   199684 flat_x [8388608] float  (optional)
#define WS_ZERO_FLOATS 67588   // = 16897 float4 exactly
#define WS_FLAT_OFF 199684
#define WS_NEED_FLAT ((size_t)(WS_FLAT_OFF + QELEMS) * 4)

// Pack embed into 32x32x16 MFMA A-fragment layout (fp16 split), compute
// enorm[k] = -0.5*||e_k||^2 (LDS reduction), AND zero the ws accumulator
// region (replaces the hipMemsetAsync node; stream order protects readers).
__global__ __launch_bounds__(256) void vq_epack_kernel(const float* __restrict__ embed,
                                                       _Float16* __restrict__ epk,
                                                       float* __restrict__ enorm,
                                                       float4* __restrict__ wsz) {
    __shared__ float sp[256];
    const int tid  = threadIdx.x;
    const int ct   = blockIdx.x;                 // 0..31
    const int gtid = ct * 256 + tid;             // 0..8191
    for (int i = gtid; i < WS_ZERO_FLOATS / 4; i += 8192)
        wsz[i] = float4{0.f, 0.f, 0.f, 0.f};

    const int kc   = (tid >> 6) & 3;
    const int lane = tid & 63;
    const int c    = ct * 32 + (lane & 31);
    const int d0   = kc * 16 + ((lane >> 5) << 3);
    const float* er = embed + c * 64 + d0;
    float4 f0 = *(const float4*)(er);
    float4 f1 = *(const float4*)(er + 4);
    float va[8] = {f0.x, f0.y, f0.z, f0.w, f1.x, f1.y, f1.z, f1.w};
    half8 h8, l8;
    float s = 0.f;
#pragma unroll
    for (int j = 0; j < 8; ++j) {
        s += va[j] * va[j];
        _Float16 ah = (_Float16)va[j];
        h8[j] = ah;
        l8[j] = (_Float16)(va[j] - (float)ah);
    }
    half8* o = (half8*)epk;
    int base = ct * 512 + kc * 64 + lane;
    o[base]       = h8;
    o[base + 256] = l8;
    sp[tid] = s;
    __syncthreads();
    if (tid < 32) {
        float tsum = 0.f;
#pragma unroll
        for (int k = 0; k < 8; ++k) tsum += sp[tid + k * 32];
        enorm[ct * 32 + tid] = -0.5f * tsum;
    }
}

// MFMA argmin, 32x32x16 tiles (frozen structure, R6/R8: ~80us): 512 blocks x
// 512 threads; wave owns 32 pixels; x-tile staged in LDS (xsT[d][row], pad 257)
// -> full-line coalesced flat_x dump + LDS-sourced B-frags. Min-update uses
// v_med3_f32 for second-best (4 VALU ops/eval).
__global__ __launch_bounds__(512, 4) void vq_argmin_mfma(
    const float* __restrict__ in,        // [32][64][64][64] NCHW
    const float* __restrict__ embed,
    const float* __restrict__ enorm,     // -0.5*||e||^2
    const _Float16* __restrict__ epk,
    float* __restrict__ out_quant,
    float* __restrict__ out_idx,
    int*   __restrict__ counts_i,
    float* __restrict__ sumsq,
    float* __restrict__ flat_x,          // or nullptr
    int*   __restrict__ wlist,
    int*   __restrict__ wcount)
{
    __shared__ float xs_lds[64 * 257];   // 64.25 KB  x-tile, [d][row] padded
    __shared__ float en_s[KCODES];       // 4 KB  (-0.5*||e||^2)
    __shared__ int   hist[KCODES];       // 4 KB
    __shared__ int   widx[256];          // 1 KB
    __shared__ float wv1[256];           // 1 KB
    __shared__ float xn_s[256];          // 1 KB
    __shared__ float rsum[512];          // 2 KB

    const int t    = threadIdx.x;
    const int blk  = blockIdx.x;         // 0..511 ; block = rows [blk*256, +256)
    const int lane = t & 63;
    const int w    = t >> 6;
    const int hl   = lane >> 5;          // 0/1 half-lane group

    for (int i = t; i < KCODES; i += 512) { en_s[i] = enorm[i]; hist[i] = 0; }

    // phase 1: read in (coalesced 256B instrs) -> xnorm partials + LDS stage
    const int rloc = t & 255;
    const int dhl  = t >> 8;             // 0/1 -> dims [dhl*32, +32)
    const int row0 = (blk << 8) + rloc;
    const int b0 = row0 >> 12, rem0 = row0 & 4095;
    {
        const float* pb = in + b0 * 262144 + (dhl << 5) * 4096 + rem0;
        float xn = 0.f;
#pragma unroll
        for (int d4 = 0; d4 < 8; ++d4) {
            float4 v;
            v.x = pb[(d4 * 4 + 0) * 4096];
            v.y = pb[(d4 * 4 + 1) * 4096];
            v.z = pb[(d4 * 4 + 2) * 4096];
            v.w = pb[(d4 * 4 + 3) * 4096];
            xn += v.x * v.x + v.y * v.y + v.z * v.z + v.w * v.w;
            int dp = (dhl << 5) + (d4 << 2);
            xs_lds[(dp + 0) * 257 + rloc] = v.x;
            xs_lds[(dp + 1) * 257 + rloc] = v.y;
            xs_lds[(dp + 2) * 257 + rloc] = v.z;
            xs_lds[(dp + 3) * 257 + rloc] = v.w;
        }
        rsum[t] = xn;
    }
    __syncthreads();   // xs_lds / en_s / hist / rsum ready
    if (t < 256) xn_s[t] = rsum[t] + rsum[t + 256];   // read by phase 5 (after next barrier)

    // phase 2a: B-frags from LDS. B[k][n]: n = lane&31 (pixel), k = hl*8+j.
    half8 xh[4], xl[4];
    {
        int rowl = (w << 5) + (lane & 31);            // block-local row
#pragma unroll
        for (int kc = 0; kc < 4; ++kc) {
#pragma unroll
            for (int j = 0; j < 8; ++j) {
                float xv = xs_lds[(kc * 16 + (hl << 3) + j) * 257 + rowl];
                _Float16 hv = (_Float16)xv;
                xh[kc][j] = hv;
                xl[kc][j] = (_Float16)(xv - (float)hv);
            }
        }
    }

    // phase 2b: flat_x dump, full-line coalesced (1 KB contiguous per instr).
    // No barrier after: stores drain under the tile loop.
    if (flat_x) {
        const int ch   = lane & 15;
        const int rsub = lane >> 4;
#pragma unroll
        for (int i = 0; i < 8; ++i) {
            int rowl = (w << 5) + (i << 2) + rsub;
            float4 v;
            v.x = xs_lds[(ch * 4 + 0) * 257 + rowl];
            v.y = xs_lds[(ch * 4 + 1) * 257 + rowl];
            v.z = xs_lds[(ch * 4 + 2) * 257 + rowl];
            v.w = xs_lds[(ch * 4 + 3) * 257 + rowl];
            *(float4*)(flat_x + (((size_t)((blk << 8) + rowl)) << 6) + (ch << 2)) = v;
        }
    }

    // phase 3: stream 32 code tiles; track top-2 of acc (maximize) per pixel
    float m1 = -3.4e38f, m2 = -3.4e38f;
    int   ip = 0;                        // packed per-lane id: ct*16 + r

    const half8* epk8 = (const half8*)epk;
    for (int ct = 0; ct < 32; ++ct) {
        const int abase = ct * 512 + lane;
        half8 ah0 = epk8[abase];
        half8 ah1 = epk8[abase + 64];
        half8 ah2 = epk8[abase + 128];
        half8 ah3 = epk8[abase + 192];
        half8 al0 = epk8[abase + 256];
        half8 al1 = epk8[abase + 320];
        half8 al2 = epk8[abase + 384];
        half8 al3 = epk8[abase + 448];
        // C-seed: acc[g*4+i] = en_s[ct*32 + 4*hl + 8*g + i]
        const float* eb = &en_s[ct * 32 + (hl << 2)];
        floatx4 e0 = *(const floatx4*)(eb);
        floatx4 e1 = *(const floatx4*)(eb + 8);
        floatx4 e2 = *(const floatx4*)(eb + 16);
        floatx4 e3 = *(const floatx4*)(eb + 24);
        floatx16 acc;
#pragma unroll
        for (int i = 0; i < 4; ++i) {
            acc[i]      = e0[i];
            acc[4 + i]  = e1[i];
            acc[8 + i]  = e2[i];
            acc[12 + i] = e3[i];
        }
        acc = __builtin_amdgcn_mfma_f32_32x32x16_f16(ah0, xh[0], acc, 0, 0, 0);
        acc = __builtin_amdgcn_mfma_f32_32x32x16_f16(ah1, xh[1], acc, 0, 0, 0);
        acc = __builtin_amdgcn_mfma_f32_32x32x16_f16(ah2, xh[2], acc, 0, 0, 0);
        acc = __builtin_amdgcn_mfma_f32_32x32x16_f16(ah3, xh[3], acc, 0, 0, 0);
        acc = __builtin_amdgcn_mfma_f32_32x32x16_f16(al0, xh[0], acc, 0, 0, 0);
        acc = __builtin_amdgcn_mfma_f32_32x32x16_f16(al1, xh[1], acc, 0, 0, 0);
        acc = __builtin_amdgcn_mfma_f32_32x32x16_f16(al2, xh[2], acc, 0, 0, 0);
        acc = __builtin_amdgcn_mfma_f32_32x32x16_f16(al3, xh[3], acc, 0, 0, 0);
        acc = __builtin_amdgcn_mfma_f32_32x32x16_f16(ah0, xl[0], acc, 0, 0, 0);
        acc = __builtin_amdgcn_mfma_f32_32x32x16_f16(ah1, xl[1], acc, 0, 0, 0);
        acc = __builtin_amdgcn_mfma_f32_32x32x16_f16(ah2, xl[2], acc, 0, 0, 0);
        acc = __builtin_amdgcn_mfma_f32_32x32x16_f16(ah3, xl[3], acc, 0, 0, 0);
        const int kb = ct << 4;
#pragma unroll
        for (int r = 0; r < 16; ++r) {
            float a = acc[r];
            m2 = __builtin_amdgcn_fmed3f(a, m1, m2);  // new 2nd-best (m1>=m2 inv.)
            if (a > m1) ip = kb + r;              // strict: first hit keeps lowest code
            m1 = fmaxf(m1, a);
        }
    }

    // phase 4: cross-half-lane merge (pixel lives in lanes l and l+32)
    {
        int rr = ip & 15, ct = ip >> 4;
        int ai = ct * 32 + (rr & 3) + ((rr >> 2) << 3) + (hl << 2);   // true code
        float a1v = m1, a2v = m2;
        float o1 = __shfl_xor(a1v, 32, 64);
        int   oi = __shfl_xor(ai, 32, 64);
        float o2 = __shfl_xor(a2v, 32, 64);
        if (o1 > a1v || (o1 == a1v && oi < ai)) {
            a2v = fmaxf(a1v, o2); a1v = o1; ai = oi;
        } else {
            a2v = fmaxf(a2v, o1);
        }
        if (lane < 32) {
            int pl  = (w << 5) + lane;
            int row = (blk << 8) + pl;
            widx[pl] = ai;
            wv1[pl]  = -2.0f * a1v;                   // = dv_min
            out_idx[row] = (float)ai;
            atomicAdd(&hist[ai], 1);
            if (2.0f * (a1v - a2v) < TAU) {           // dv2 - dv1 < TAU
                int pos = atomicAdd(wcount, 1);
                if (pos < WCAP) wlist[pos] = row;
            }
        }
    }
    __syncthreads();

    // phase 5: hist flush + quant write + sumsq (dv_min + |x|^2)
    for (int i = t; i < KCODES; i += 512) {
        int v = hist[i];
        if (v) atomicAdd(&counts_i[i], v);
    }
    {
        int k = widx[rloc];
        const float4* eq = (const float4*)(embed + (k << 6) + (dhl << 5));
        float* ob = out_quant + b0 * 262144 + (dhl << 5) * 4096 + rem0;
#pragma unroll
        for (int d4 = 0; d4 < 8; ++d4) {
            float4 e4v = eq[d4];
            ob[(d4 * 4 + 0) * 4096] = e4v.x;
            ob[(d4 * 4 + 1) * 4096] = e4v.y;
            ob[(d4 * 4 + 2) * 4096] = e4v.z;
            ob[(d4 * 4 + 3) * 4096] = e4v.w;
        }
        rsum[t] = (t < 256) ? (wv1[t] + xn_s[t]) : 0.f;
    }
    __syncthreads();
    for (int s = 256; s > 0; s >>= 1) {
        if (t < s) rsum[t] += rsum[t + s];
        __syncthreads();
    }
    if (t == 0) atomicAdd(sumsq, rsum[0]);
}

// Refine of contested pixels, fp32 direct distances (error ~1e-5 << TAU=1e-3).
// Patches idx/quant/counts/loss; restores wlist=0 (dwacc alias).
__global__ __launch_bounds__(256) void vq_refine_kernel(
    const float* __restrict__ embed,
    const float* __restrict__ in,
    const float* __restrict__ flat_x,    // may be null
    float* __restrict__ out_idx,
    float* __restrict__ out_quant,
    int*   __restrict__ counts_i,
    float* __restrict__ scal,            // [0]=sumsq
    int*   __restrict__ wlist,
    const int* __restrict__ wcount)
{
    const int lane = threadIdx.x & 63;
    const int gw   = (blockIdx.x << 2) + (threadIdx.x >> 6);
    const int nw   = gridDim.x << 2;
    int count = *wcount;
    if (count > WCAP) count = WCAP;

    for (int e = gw; e < count; e += nw) {
        int r = wlist[e];
        int b = r >> 12, rem = r & 4095;
        float4 xr[16];
        if (flat_x) {
            const float4* xs4 = (const float4*)(flat_x + ((size_t)r << 6));
#pragma unroll
            for (int qq = 0; qq < 16; ++qq) xr[qq] = xs4[qq];
        } else {
#pragma unroll
            for (int qq = 0; qq < 16; ++qq) {
                xr[qq].x = in[b * 262144 + (qq * 4 + 0) * 4096 + rem];
                xr[qq].y = in[b * 262144 + (qq * 4 + 1) * 4096 + rem];
                xr[qq].z = in[b * 262144 + (qq * 4 + 2) * 4096 + rem];
                xr[qq].w = in[b * 262144 + (qq * 4 + 3) * 4096 + rem];
            }
        }
        float bv = 3.4e38f;
        int   bi = 0;
        for (int j = 0; j < 16; ++j) {
            int c = (j << 6) + lane;
            const float4* er = (const float4*)(embed + (c << 6));
            float acc = 0.f;
#pragma unroll
            for (int qq = 0; qq < 16; ++qq) {
                float4 ev = er[qq];
                float d0 = xr[qq].x - ev.x;
                float d1 = xr[qq].y - ev.y;
                float d2 = xr[qq].z - ev.z;
                float d3 = xr[qq].w - ev.w;
                acc += d0 * d0 + d1 * d1 + d2 * d2 + d3 * d3;
            }
            if (acc < bv) { bv = acc; bi = c; }
        }
#pragma unroll
        for (int off = 1; off < 64; off <<= 1) {
            float ov = __shfl_xor(bv, off, 64);
            int   oi = __shfl_xor(bi, off, 64);
            if (ov < bv || (ov == bv && oi < bi)) { bv = ov; bi = oi; }
        }
        int oldi = (int)out_idx[r];
        if (bi != oldi) {
            float xd = flat_x ? flat_x[((size_t)r << 6) + lane]
                              : in[b * 262144 + lane * 4096 + rem];
            float en_ = embed[(bi << 6) + lane];
            float eo_ = embed[(oldi << 6) + lane];
            out_quant[b * 262144 + lane * 4096 + rem] = en_;
            float dl = (en_ - xd) * (en_ - xd) - (eo_ - xd) * (eo_ - xd);
#pragma unroll
            for (int off = 1; off < 64; off <<= 1) dl += __shfl_xor(dl, off, 64);
            if (lane == 0) {
                out_idx[r] = (float)bi;
                atomicAdd(&scal[0], dl);
                atomicSub(&counts_i[oldi], 1);
                atomicAdd(&counts_i[bi], 1);
            }
        }
        if (lane == 0) wlist[e] = 0;   // restore dwacc zero
    }
}

// ---- tail ----
__global__ __launch_bounds__(256) void vq_scatter_kernel(
    const float* __restrict__ idxf,
    const int*   __restrict__ counts_i,
    int* __restrict__ cursor,
    int* __restrict__ keys)
{
    __shared__ int lstarts[KCODES];
    __shared__ int lh[KCODES];
    __shared__ int part[256];
    const int t   = threadIdx.x;
    const int blk = blockIdx.x;

    int4 c4 = *(const int4*)(counts_i + (t << 2));
    part[t] = c4.x + c4.y + c4.z + c4.w;
    {
        int tb = t << 2;
        lh[tb] = 0; lh[tb + 1] = 0; lh[tb + 2] = 0; lh[tb + 3] = 0;
    }
    __syncthreads();
    for (int off = 1; off < 256; off <<= 1) {
        int v   = part[t];
        int add = (t >= off) ? part[t - off] : 0;
        __syncthreads();
        part[t] = v + add;
        __syncthreads();
    }
    {
        int base = (t == 0) ? 0 : part[t - 1];
        int tb = t << 2;
        lstarts[tb]     = base;
        lstarts[tb + 1] = base + c4.x;
        lstarts[tb + 2] = base + c4.x + c4.y;
        lstarts[tb + 3] = base + c4.x + c4.y + c4.z;
    }
    __syncthreads();

    const int i0 = (blk << 9) + t;
    const int i1 = i0 + 256;
    int code0 = (int)idxf[i0];
    int rank0 = atomicAdd(&lh[code0], 1);
    int code1 = (int)idxf[i1];
    int rank1 = atomicAdd(&lh[code1], 1);
    __syncthreads();
    for (int k = t; k < KCODES; k += 256) {
        int cnt = lh[k];
        if (cnt) lh[k] = lstarts[k] + atomicAdd(&cursor[k], cnt);
    }
    __syncthreads();
    keys[lh[code0] + rank0] = (code0 << 17) | i0;
    keys[lh[code1] + rank1] = (code1 << 17) | i1;
}

__global__ __launch_bounds__(256) void vq_dw_kernel(
    const float* __restrict__ flat_x,
    const int*   __restrict__ keys,
    float* __restrict__ dwacc)
{
    const int t   = threadIdx.x;
    const int blk = blockIdx.x;
    const int wv  = t >> 6, d = t & 63;
    const int base = (blk << 9) + (wv << 7);

    int key   = keys[base];
    int c_cur = key >> 17;
    int r     = key & 0x1FFFF;
    float acc = 0.f;
#pragma unroll 4
    for (int m = 0; m < 128; ++m) {
        float x = flat_x[((size_t)r << 6) + d];
        int nkey = (m < 127) ? keys[base + m + 1] : -1;
        int c_n  = nkey >> 17;
        int r_n  = nkey & 0x1FFFF;
        acc += x;
        if (c_n != c_cur) {
            atomicAdd(&dwacc[(c_cur << 6) + d], acc);
            acc = 0.f;
            c_cur = c_n;
        }
        r = r_n;
    }
}

__global__ __launch_bounds__(256) void vq_dw_nchw_kernel(
    const float* __restrict__ in,
    const int*   __restrict__ keys,
    float* __restrict__ dwacc)
{
    const int t   = threadIdx.x;
    const int blk = blockIdx.x;
    const int wv  = t >> 6, d = t & 63;
    const int base = (blk << 9) + (wv << 7);

    int key   = keys[base];
    int c_cur = key >> 17;
    int r     = key & 0x1FFFF;
    float acc = 0.f;
    for (int m = 0; m < 128; ++m) {
        int b = r >> 12, rem = r & 4095;
        float x = in[b * 262144 + d * 4096 + rem];
        int nkey = (m < 127) ? keys[base + m + 1] : -1;
        int c_n  = nkey >> 17;
        int r_n  = nkey & 0x1FFFF;
        acc += x;
        if (c_n != c_cur) {
            atomicAdd(&dwacc[(c_cur << 6) + d], acc);
            acc = 0.f;
            c_cur = c_n;
        }
        r = r_n;
    }
}

// Fused finalize (replaces fin_a + fin_b): every block redundantly computes
// n = sum(ncs) from counts+ema_cs (no cross-block dependency); block 0 also
// does entropy, o_ncs, loss, perplexity.
__global__ __launch_bounds__(256) void vq_fin_kernel(
    const float* __restrict__ ema_cs,
    const float* __restrict__ ema_w,
    const int*   __restrict__ counts_i,
    const float* __restrict__ dwacc,
    const float* __restrict__ scal,
    float* __restrict__ out)
{
    __shared__ float r1[256], r2[256];
    const int t = threadIdx.x;
    float* o_loss  = out + QELEMS;
    float* o_perp  = out + QELEMS + 1;
    float* o_ncs   = out + QELEMS + 2 + NTOT;
    float* o_emaw  = o_ncs + KCODES;
    float* o_embed = o_emaw + KCODES * DIM;

    int4   ci = *(const int4*)(counts_i + (t << 2));
    float4 ec = *(const float4*)(ema_cs + (t << 2));
    float ncs0 = 0.99f * ec.x + 0.01f * (float)ci.x;
    float ncs1 = 0.99f * ec.y + 0.01f * (float)ci.y;
    float ncs2 = 0.99f * ec.z + 0.01f * (float)ci.z;
    float ncs3 = 0.99f * ec.w + 0.01f * (float)ci.w;
    r1[t] = ncs0 + ncs1 + ncs2 + ncs3;
    {
        float p0 = (float)ci.x / (float)NTOT, p1 = (float)ci.y / (float)NTOT;
        float p2 = (float)ci.z / (float)NTOT, p3 = (float)ci.w / (float)NTOT;
        r2[t] = p0 * logf(p0 + 1e-10f) + p1 * logf(p1 + 1e-10f)
              + p2 * logf(p2 + 1e-10f) + p3 * logf(p3 + 1e-10f);
    }
    if (blockIdx.x == 0) {
        float4* on4 = (float4*)(o_ncs + (t << 2));
        *on4 = float4{ncs0, ncs1, ncs2, ncs3};
    }
    __syncthreads();
    for (int s = 128; s > 0; s >>= 1) {
        if (t < s) { r1[t] += r1[t + s]; r2[t] += r2[t + s]; }
        __syncthreads();
    }
    float n = r1[0];
    float denom = n + (float)KCODES * 1e-5f;
#pragma unroll
    for (int u = 0; u < 8; ++u) {
        int i = (blockIdx.x << 11) + (u << 8) + t;
        int k = i >> 6;
        float c   = (float)counts_i[k];
        float ncs = 0.99f * ema_cs[k] + 0.01f * c;
        float cs  = (ncs + 1e-5f) / denom * n;
        cs = fmaxf(cs, 1e-5f);
        float w = 0.99f * ema_w[i] + 0.01f * dwacc[i];
        o_emaw[i]  = w;
        o_embed[i] = w / cs;
    }
    if (blockIdx.x == 0 && t == 0) {
        o_loss[0] = 0.25f * scal[0] / (float)QELEMS;
        o_perp[0] = expf(-r2[0]);
    }
}

extern "C" void kernel_launch(void* const* d_in, const int* in_sizes, int n_in,
                              void* d_out, int out_size, void* d_ws, size_t ws_size,
                              hipStream_t stream) {
    const float* in     = (const float*)d_in[0];
    const float* embed  = (const float*)d_in[1];
    const float* ema_cs = (const float*)d_in[2];
    const float* ema_w  = (const float*)d_in[3];
    float* out = (float*)d_out;
    float* ws  = (float*)d_ws;

    int*   counts_i = (int*)ws;              // 1024
    float* scal     = ws + 1024;             // 3 + wcount at 1027
    int*   wcount   = (int*)ws + 1027;
    int*   cursor   = (int*)ws + 1028;       // 1024
    float* dwacc    = ws + 2052;             // 65536 (worklist alias)
    int*   wlist    = (int*)ws + 2052;
    float* enorm    = ws + 67588;            // 1024
    _Float16* epk   = (_Float16*)(ws + 68612);   // 131072 halves (argmin phase)
    int*   keys     = (int*)ws + 68612;      // tail phase, aliases epk
    const bool use_flat = ws_size >= WS_NEED_FLAT;
    float* flat_x   = use_flat ? (ws + WS_FLAT_OFF) : (float*)0;
    float* o_idx    = out + QELEMS + 2;

    vq_epack_kernel<<<32, 256, 0, stream>>>(embed, epk, enorm, (float4*)ws);
    vq_argmin_mfma<<<512, 512, 0, stream>>>(in, embed, enorm, epk, out, o_idx,
                                            counts_i, scal, flat_x, wlist, wcount);
    vq_refine_kernel<<<128, 256, 0, stream>>>(embed, in, flat_x, o_idx, out,
                                              counts_i, scal, wlist, wcount);
    vq_scatter_kernel<<<256, 256, 0, stream>>>(o_idx, counts_i, cursor, keys);
    if (use_flat)
        vq_dw_kernel<<<256, 256, 0, stream>>>(flat_x, keys, dwacc);
    else
        vq_dw_nchw_kernel<<<256, 256, 0, stream>>>(in, keys, dwacc);
    vq_fin_kernel<<<32, 256, 0, stream>>>(ema_cs, ema_w, counts_i, dwacc, scal, out);
}

// Round 10
// 217.950 us; speedup vs baseline: 8.2062x; 1.1306x over previous
//
#include <hip/hip_runtime.h>
#include <math.h>

#define KCODES 1024
#define DIM 64
#define NTOT 131072          // 32*64*64 rows
#define QELEMS 8388608       // 32*64*64*64
#define TAU 1e-3f            // contested-margin threshold (>> fp16-split error bound)
#define WCAP 65536           // worklist capacity (aliases dwacc region)

typedef _Float16 half8 __attribute__((ext_vector_type(8)));
typedef float floatx4 __attribute__((ext_vector_type(4)));
typedef float floatx16 __attribute__((ext_vector_type(16)));

// ws layout (4B units):
//   0      counts_i [1024] int     (zeroed by epack)
//   1024   scal [3]: sumsq,nsum,ent; [1027] wcount int (zeroed by epack)
//   1028   cursor [1024] int       (zeroed by epack)
//   2052   dwacc [65536] float     (zeroed by epack; aliases refine worklist, re-zeroed)
//   67588  enorm [1024] float      (holds -0.5*||e||^2)
//   68612  epk [65536 floats = 131072 halves]   (argmin phase)
//   68612  keys [131072] int                    (tail phase, aliases epk)
//   199684 flat_x [8388608] float  (optional)
#define WS_ZERO_FLOATS 67588   // = 16897 float4 exactly
#define WS_FLAT_OFF 199684
#define WS_NEED_FLAT ((size_t)(WS_FLAT_OFF + QELEMS) * 4)

#define XS_STRIDE 260          // float4-aligned LDS row stride (pad 4)

// Pack embed into 32x32x16 MFMA A-fragment layout (fp16 split), compute
// enorm[k] = -0.5*||e_k||^2 (LDS reduction), AND zero the ws accumulator
// region (replaces the hipMemsetAsync node; stream order protects readers).
__global__ __launch_bounds__(256) void vq_epack_kernel(const float* __restrict__ embed,
                                                       _Float16* __restrict__ epk,
                                                       float* __restrict__ enorm,
                                                       float4* __restrict__ wsz) {
    __shared__ float sp[256];
    const int tid  = threadIdx.x;
    const int ct   = blockIdx.x;                 // 0..31
    const int gtid = ct * 256 + tid;             // 0..8191
    for (int i = gtid; i < WS_ZERO_FLOATS / 4; i += 8192)
        wsz[i] = float4{0.f, 0.f, 0.f, 0.f};

    const int kc   = (tid >> 6) & 3;
    const int lane = tid & 63;
    const int c    = ct * 32 + (lane & 31);
    const int d0   = kc * 16 + ((lane >> 5) << 3);
    const float* er = embed + c * 64 + d0;
    float4 f0 = *(const float4*)(er);
    float4 f1 = *(const float4*)(er + 4);
    float va[8] = {f0.x, f0.y, f0.z, f0.w, f1.x, f1.y, f1.z, f1.w};
    half8 h8, l8;
    float s = 0.f;
#pragma unroll
    for (int j = 0; j < 8; ++j) {
        s += va[j] * va[j];
        _Float16 ah = (_Float16)va[j];
        h8[j] = ah;
        l8[j] = (_Float16)(va[j] - (float)ah);
    }
    half8* o = (half8*)epk;
    int base = ct * 512 + kc * 64 + lane;
    o[base]       = h8;
    o[base + 256] = l8;
    sp[tid] = s;
    __syncthreads();
    if (tid < 32) {
        float tsum = 0.f;
#pragma unroll
        for (int k = 0; k < 8; ++k) tsum += sp[tid + k * 32];
        enorm[ct * 32 + tid] = -0.5f * tsum;
    }
}

// MFMA argmin, 32x32x16 tiles: 512 blocks x 512 threads; wave owns 32 pixels.
// Phase 1 is float4-vectorized (wave w = dim-group w, lane = 4-row group):
// 1 KB contiguous per load instr, b128 LDS stores. xnorm computed in phase 2a.
__global__ __launch_bounds__(512, 4) void vq_argmin_mfma(
    const float* __restrict__ in,        // [32][64][64][64] NCHW
    const float* __restrict__ embed,
    const float* __restrict__ enorm,     // -0.5*||e||^2
    const _Float16* __restrict__ epk,
    float* __restrict__ out_quant,
    float* __restrict__ out_idx,
    int*   __restrict__ counts_i,
    float* __restrict__ sumsq,
    float* __restrict__ flat_x,          // or nullptr
    int*   __restrict__ wlist,
    int*   __restrict__ wcount)
{
    __shared__ float xs_lds[64 * XS_STRIDE];   // 66.56 KB  x-tile [d][row]
    __shared__ float en_s[KCODES];       // 4 KB  (-0.5*||e||^2)
    __shared__ int   hist[KCODES];       // 4 KB
    __shared__ int   widx[256];          // 1 KB
    __shared__ float wv1[256];           // 1 KB
    __shared__ float xn_s[256];          // 1 KB
    __shared__ float rsum[512];          // 2 KB

    const int t    = threadIdx.x;
    const int blk  = blockIdx.x;         // 0..511 ; block = rows [blk*256, +256)
    const int lane = t & 63;
    const int w    = t >> 6;
    const int hl   = lane >> 5;          // 0/1 half-lane group

    for (int i = t; i < KCODES; i += 512) { en_s[i] = enorm[i]; hist[i] = 0; }

    // phase 1: in -> LDS stage, float4 coalesced. Wave w handles dims
    // [w*8, +8); lane = 4-row group (rows lane*4..+3). Blocks never cross an
    // image boundary (4096 rows/image, 256 rows/block).
    const int rloc = t & 255;
    const int dhl  = t >> 8;             // 0/1 -> dims [dhl*32, +32) (phase 5)
    const int row0 = (blk << 8) + rloc;
    const int b0 = row0 >> 12, rem0 = row0 & 4095;
    {
        const int prow = (blk << 8) + (lane << 2);
        const int pb   = prow >> 12, prem = prow & 4095;
        const float* pbase = in + pb * 262144 + prem;
#pragma unroll
        for (int j = 0; j < 8; ++j) {
            float4 v = *(const float4*)(pbase + (w * 8 + j) * 4096);
            *(float4*)&xs_lds[(w * 8 + j) * XS_STRIDE + (lane << 2)] = v;
        }
    }
    __syncthreads();   // xs_lds / en_s / hist ready

    // phase 2a: B-frags from LDS + xnorm. B[k][n]: n = lane&31, k = hl*8+j.
    // Lanes l and l+32 together cover all 64 dims of pixel rowl exactly once.
    half8 xh[4], xl[4];
    float xn = 0.f;
    {
        int rowl = (w << 5) + (lane & 31);            // block-local row
#pragma unroll
        for (int kc = 0; kc < 4; ++kc) {
#pragma unroll
            for (int j = 0; j < 8; ++j) {
                float xv = xs_lds[(kc * 16 + (hl << 3) + j) * XS_STRIDE + rowl];
                xn += xv * xv;
                _Float16 hv = (_Float16)xv;
                xh[kc][j] = hv;
                xl[kc][j] = (_Float16)(xv - (float)hv);
            }
        }
        xn += __shfl_xor(xn, 32, 64);                 // full 64-dim norm
    }

    // phase 2b: flat_x dump, full-line coalesced (1 KB contiguous per instr).
    // No barrier after: stores drain under the tile loop.
    if (flat_x) {
        const int ch   = lane & 15;
        const int rsub = lane >> 4;
#pragma unroll
        for (int i = 0; i < 8; ++i) {
            int rowl = (w << 5) + (i << 2) + rsub;
            float4 v;
            v.x = xs_lds[(ch * 4 + 0) * XS_STRIDE + rowl];
            v.y = xs_lds[(ch * 4 + 1) * XS_STRIDE + rowl];
            v.z = xs_lds[(ch * 4 + 2) * XS_STRIDE + rowl];
            v.w = xs_lds[(ch * 4 + 3) * XS_STRIDE + rowl];
            *(float4*)(flat_x + (((size_t)((blk << 8) + rowl)) << 6) + (ch << 2)) = v;
        }
    }

    // phase 3: stream 32 code tiles; track top-2 of acc (maximize) per pixel
    float m1 = -3.4e38f, m2 = -3.4e38f;
    int   ip = 0;                        // packed per-lane id: ct*16 + r

    const half8* epk8 = (const half8*)epk;
    for (int ct = 0; ct < 32; ++ct) {
        const int abase = ct * 512 + lane;
        half8 ah0 = epk8[abase];
        half8 ah1 = epk8[abase + 64];
        half8 ah2 = epk8[abase + 128];
        half8 ah3 = epk8[abase + 192];
        half8 al0 = epk8[abase + 256];
        half8 al1 = epk8[abase + 320];
        half8 al2 = epk8[abase + 384];
        half8 al3 = epk8[abase + 448];
        // C-seed: acc[g*4+i] = en_s[ct*32 + 4*hl + 8*g + i]
        const float* eb = &en_s[ct * 32 + (hl << 2)];
        floatx4 e0 = *(const floatx4*)(eb);
        floatx4 e1 = *(const floatx4*)(eb + 8);
        floatx4 e2 = *(const floatx4*)(eb + 16);
        floatx4 e3 = *(const floatx4*)(eb + 24);
        floatx16 acc;
#pragma unroll
        for (int i = 0; i < 4; ++i) {
            acc[i]      = e0[i];
            acc[4 + i]  = e1[i];
            acc[8 + i]  = e2[i];
            acc[12 + i] = e3[i];
        }
        acc = __builtin_amdgcn_mfma_f32_32x32x16_f16(ah0, xh[0], acc, 0, 0, 0);
        acc = __builtin_amdgcn_mfma_f32_32x32x16_f16(ah1, xh[1], acc, 0, 0, 0);
        acc = __builtin_amdgcn_mfma_f32_32x32x16_f16(ah2, xh[2], acc, 0, 0, 0);
        acc = __builtin_amdgcn_mfma_f32_32x32x16_f16(ah3, xh[3], acc, 0, 0, 0);
        acc = __builtin_amdgcn_mfma_f32_32x32x16_f16(al0, xh[0], acc, 0, 0, 0);
        acc = __builtin_amdgcn_mfma_f32_32x32x16_f16(al1, xh[1], acc, 0, 0, 0);
        acc = __builtin_amdgcn_mfma_f32_32x32x16_f16(al2, xh[2], acc, 0, 0, 0);
        acc = __builtin_amdgcn_mfma_f32_32x32x16_f16(al3, xh[3], acc, 0, 0, 0);
        acc = __builtin_amdgcn_mfma_f32_32x32x16_f16(ah0, xl[0], acc, 0, 0, 0);
        acc = __builtin_amdgcn_mfma_f32_32x32x16_f16(ah1, xl[1], acc, 0, 0, 0);
        acc = __builtin_amdgcn_mfma_f32_32x32x16_f16(ah2, xl[2], acc, 0, 0, 0);
        acc = __builtin_amdgcn_mfma_f32_32x32x16_f16(ah3, xl[3], acc, 0, 0, 0);
        const int kb = ct << 4;
#pragma unroll
        for (int r = 0; r < 16; ++r) {
            float a = acc[r];
            m2 = __builtin_amdgcn_fmed3f(a, m1, m2);  // new 2nd-best (m1>=m2 inv.)
            if (a > m1) ip = kb + r;              // strict: first hit keeps lowest code
            m1 = fmaxf(m1, a);
        }
    }

    // phase 4: cross-half-lane merge (pixel lives in lanes l and l+32)
    {
        int rr = ip & 15, ct = ip >> 4;
        int ai = ct * 32 + (rr & 3) + ((rr >> 2) << 3) + (hl << 2);   // true code
        float a1v = m1, a2v = m2;
        float o1 = __shfl_xor(a1v, 32, 64);
        int   oi = __shfl_xor(ai, 32, 64);
        float o2 = __shfl_xor(a2v, 32, 64);
        if (o1 > a1v || (o1 == a1v && oi < ai)) {
            a2v = fmaxf(a1v, o2); a1v = o1; ai = oi;
        } else {
            a2v = fmaxf(a2v, o1);
        }
        if (lane < 32) {
            int pl  = (w << 5) + lane;
            int row = (blk << 8) + pl;
            widx[pl] = ai;
            wv1[pl]  = -2.0f * a1v;                   // = dv_min
            xn_s[pl] = xn;
            out_idx[row] = (float)ai;
            atomicAdd(&hist[ai], 1);
            if (2.0f * (a1v - a2v) < TAU) {           // dv2 - dv1 < TAU
                int pos = atomicAdd(wcount, 1);
                if (pos < WCAP) wlist[pos] = row;
            }
        }
    }
    __syncthreads();

    // phase 5: hist flush + quant write + sumsq (dv_min + |x|^2)
    for (int i = t; i < KCODES; i += 512) {
        int v = hist[i];
        if (v) atomicAdd(&counts_i[i], v);
    }
    {
        int k = widx[rloc];
        const float4* eq = (const float4*)(embed + (k << 6) + (dhl << 5));
        float* ob = out_quant + b0 * 262144 + (dhl << 5) * 4096 + rem0;
#pragma unroll
        for (int d4 = 0; d4 < 8; ++d4) {
            float4 e4v = eq[d4];
            ob[(d4 * 4 + 0) * 4096] = e4v.x;
            ob[(d4 * 4 + 1) * 4096] = e4v.y;
            ob[(d4 * 4 + 2) * 4096] = e4v.z;
            ob[(d4 * 4 + 3) * 4096] = e4v.w;
        }
        rsum[t] = (t < 256) ? (wv1[t] + xn_s[t]) : 0.f;
    }
    __syncthreads();
    for (int s = 256; s > 0; s >>= 1) {
        if (t < s) rsum[t] += rsum[t + s];
        __syncthreads();
    }
    if (t == 0) atomicAdd(sumsq, rsum[0]);
}

// Refine of contested pixels, fp32 direct distances (error ~1e-5 << TAU=1e-3).
// Patches idx/quant/counts/loss; restores wlist=0 (dwacc alias).
__global__ __launch_bounds__(256) void vq_refine_kernel(
    const float* __restrict__ embed,
    const float* __restrict__ in,
    const float* __restrict__ flat_x,    // may be null
    float* __restrict__ out_idx,
    float* __restrict__ out_quant,
    int*   __restrict__ counts_i,
    float* __restrict__ scal,            // [0]=sumsq
    int*   __restrict__ wlist,
    const int* __restrict__ wcount)
{
    const int lane = threadIdx.x & 63;
    const int gw   = (blockIdx.x << 2) + (threadIdx.x >> 6);
    const int nw   = gridDim.x << 2;
    int count = *wcount;
    if (count > WCAP) count = WCAP;

    for (int e = gw; e < count; e += nw) {
        int r = wlist[e];
        int b = r >> 12, rem = r & 4095;
        float4 xr[16];
        if (flat_x) {
            const float4* xs4 = (const float4*)(flat_x + ((size_t)r << 6));
#pragma unroll
            for (int qq = 0; qq < 16; ++qq) xr[qq] = xs4[qq];
        } else {
#pragma unroll
            for (int qq = 0; qq < 16; ++qq) {
                xr[qq].x = in[b * 262144 + (qq * 4 + 0) * 4096 + rem];
                xr[qq].y = in[b * 262144 + (qq * 4 + 1) * 4096 + rem];
                xr[qq].z = in[b * 262144 + (qq * 4 + 2) * 4096 + rem];
                xr[qq].w = in[b * 262144 + (qq * 4 + 3) * 4096 + rem];
            }
        }
        float bv = 3.4e38f;
        int   bi = 0;
        for (int j = 0; j < 16; ++j) {
            int c = (j << 6) + lane;
            const float4* er = (const float4*)(embed + (c << 6));
            float acc = 0.f;
#pragma unroll
            for (int qq = 0; qq < 16; ++qq) {
                float4 ev = er[qq];
                float d0 = xr[qq].x - ev.x;
                float d1 = xr[qq].y - ev.y;
                float d2 = xr[qq].z - ev.z;
                float d3 = xr[qq].w - ev.w;
                acc += d0 * d0 + d1 * d1 + d2 * d2 + d3 * d3;
            }
            if (acc < bv) { bv = acc; bi = c; }
        }
#pragma unroll
        for (int off = 1; off < 64; off <<= 1) {
            float ov = __shfl_xor(bv, off, 64);
            int   oi = __shfl_xor(bi, off, 64);
            if (ov < bv || (ov == bv && oi < bi)) { bv = ov; bi = oi; }
        }
        int oldi = (int)out_idx[r];
        if (bi != oldi) {
            float xd = flat_x ? flat_x[((size_t)r << 6) + lane]
                              : in[b * 262144 + lane * 4096 + rem];
            float en_ = embed[(bi << 6) + lane];
            float eo_ = embed[(oldi << 6) + lane];
            out_quant[b * 262144 + lane * 4096 + rem] = en_;
            float dl = (en_ - xd) * (en_ - xd) - (eo_ - xd) * (eo_ - xd);
#pragma unroll
            for (int off = 1; off < 64; off <<= 1) dl += __shfl_xor(dl, off, 64);
            if (lane == 0) {
                out_idx[r] = (float)bi;
                atomicAdd(&scal[0], dl);
                atomicSub(&counts_i[oldi], 1);
                atomicAdd(&counts_i[bi], 1);
            }
        }
        if (lane == 0) wlist[e] = 0;   // restore dwacc zero
    }
}

// ---- tail ----
__global__ __launch_bounds__(256) void vq_scatter_kernel(
    const float* __restrict__ idxf,
    const int*   __restrict__ counts_i,
    int* __restrict__ cursor,
    int* __restrict__ keys)
{
    __shared__ int lstarts[KCODES];
    __shared__ int lh[KCODES];
    __shared__ int part[256];
    const int t   = threadIdx.x;
    const int blk = blockIdx.x;

    int4 c4 = *(const int4*)(counts_i + (t << 2));
    part[t] = c4.x + c4.y + c4.z + c4.w;
    {
        int tb = t << 2;
        lh[tb] = 0; lh[tb + 1] = 0; lh[tb + 2] = 0; lh[tb + 3] = 0;
    }
    __syncthreads();
    for (int off = 1; off < 256; off <<= 1) {
        int v   = part[t];
        int add = (t >= off) ? part[t - off] : 0;
        __syncthreads();
        part[t] = v + add;
        __syncthreads();
    }
    {
        int base = (t == 0) ? 0 : part[t - 1];
        int tb = t << 2;
        lstarts[tb]     = base;
        lstarts[tb + 1] = base + c4.x;
        lstarts[tb + 2] = base + c4.x + c4.y;
        lstarts[tb + 3] = base + c4.x + c4.y + c4.z;
    }
    __syncthreads();

    const int i0 = (blk << 9) + t;
    const int i1 = i0 + 256;
    int code0 = (int)idxf[i0];
    int rank0 = atomicAdd(&lh[code0], 1);
    int code1 = (int)idxf[i1];
    int rank1 = atomicAdd(&lh[code1], 1);
    __syncthreads();
    for (int k = t; k < KCODES; k += 256) {
        int cnt = lh[k];
        if (cnt) lh[k] = lstarts[k] + atomicAdd(&cursor[k], cnt);
    }
    __syncthreads();
    keys[lh[code0] + rank0] = (code0 << 17) | i0;
    keys[lh[code1] + rank1] = (code1 << 17) | i1;
}

// dw segment-sum over sorted keys: 1024 blocks x 256 (4096 waves = 4/CU more
// TLP than the old 1024-wave config), 32 keys/wave, one-iter x-prefetch.
// Run splits across chunk boundaries are exact (flush-at-end + atomic adds).
__global__ __launch_bounds__(256) void vq_dw_kernel(
    const float* __restrict__ flat_x,
    const int*   __restrict__ keys,
    float* __restrict__ dwacc)
{
    const int t   = threadIdx.x;
    const int blk = blockIdx.x;
    const int wv  = t >> 6, d = t & 63;
    const int base = (blk << 7) + (wv << 5);   // 32 keys per wave

    int key   = keys[base];
    int c_cur = key >> 17;
    int r     = key & 0x1FFFF;
    float x   = flat_x[((size_t)r << 6) + d];
    float acc = 0.f;
#pragma unroll 4
    for (int m = 0; m < 32; ++m) {
        int nkey = (m < 31) ? keys[base + m + 1] : -1;
        int c_n  = nkey >> 17;
        int r_n  = nkey & 0x1FFFF;
        float x_n = (m < 31) ? flat_x[((size_t)r_n << 6) + d] : 0.f;
        acc += x;
        if (c_n != c_cur) {
            atomicAdd(&dwacc[(c_cur << 6) + d], acc);
            acc = 0.f;
            c_cur = c_n;
        }
        x = x_n;
        r = r_n;
    }
}

__global__ __launch_bounds__(256) void vq_dw_nchw_kernel(
    const float* __restrict__ in,
    const int*   __restrict__ keys,
    float* __restrict__ dwacc)
{
    const int t   = threadIdx.x;
    const int blk = blockIdx.x;
    const int wv  = t >> 6, d = t & 63;
    const int base = (blk << 7) + (wv << 5);

    int key   = keys[base];
    int c_cur = key >> 17;
    int r     = key & 0x1FFFF;
    float acc = 0.f;
    for (int m = 0; m < 32; ++m) {
        int b = r >> 12, rem = r & 4095;
        float x = in[b * 262144 + d * 4096 + rem];
        int nkey = (m < 31) ? keys[base + m + 1] : -1;
        int c_n  = nkey >> 17;
        int r_n  = nkey & 0x1FFFF;
        acc += x;
        if (c_n != c_cur) {
            atomicAdd(&dwacc[(c_cur << 6) + d], acc);
            acc = 0.f;
            c_cur = c_n;
        }
        r = r_n;
    }
}

// Fused finalize: every block redundantly computes n = sum(ncs); block 0 also
// does entropy, o_ncs, loss, perplexity.
__global__ __launch_bounds__(256) void vq_fin_kernel(
    const float* __restrict__ ema_cs,
    const float* __restrict__ ema_w,
    const int*   __restrict__ counts_i,
    const float* __restrict__ dwacc,
    const float* __restrict__ scal,
    float* __restrict__ out)
{
    __shared__ float r1[256], r2[256];
    const int t = threadIdx.x;
    float* o_loss  = out + QELEMS;
    float* o_perp  = out + QELEMS + 1;
    float* o_ncs   = out + QELEMS + 2 + NTOT;
    float* o_emaw  = o_ncs + KCODES;
    float* o_embed = o_emaw + KCODES * DIM;

    int4   ci = *(const int4*)(counts_i + (t << 2));
    float4 ec = *(const float4*)(ema_cs + (t << 2));
    float ncs0 = 0.99f * ec.x + 0.01f * (float)ci.x;
    float ncs1 = 0.99f * ec.y + 0.01f * (float)ci.y;
    float ncs2 = 0.99f * ec.z + 0.01f * (float)ci.z;
    float ncs3 = 0.99f * ec.w + 0.01f * (float)ci.w;
    r1[t] = ncs0 + ncs1 + ncs2 + ncs3;
    {
        float p0 = (float)ci.x / (float)NTOT, p1 = (float)ci.y / (float)NTOT;
        float p2 = (float)ci.z / (float)NTOT, p3 = (float)ci.w / (float)NTOT;
        r2[t] = p0 * logf(p0 + 1e-10f) + p1 * logf(p1 + 1e-10f)
              + p2 * logf(p2 + 1e-10f) + p3 * logf(p3 + 1e-10f);
    }
    if (blockIdx.x == 0) {
        float4* on4 = (float4*)(o_ncs + (t << 2));
        *on4 = float4{ncs0, ncs1, ncs2, ncs3};
    }
    __syncthreads();
    for (int s = 128; s > 0; s >>= 1) {
        if (t < s) { r1[t] += r1[t + s]; r2[t] += r2[t + s]; }
        __syncthreads();
    }
    float n = r1[0];
    float denom = n + (float)KCODES * 1e-5f;
#pragma unroll
    for (int u = 0; u < 8; ++u) {
        int i = (blockIdx.x << 11) + (u << 8) + t;
        int k = i >> 6;
        float c   = (float)counts_i[k];
        float ncs = 0.99f * ema_cs[k] + 0.01f * c;
        float cs  = (ncs + 1e-5f) / denom * n;
        cs = fmaxf(cs, 1e-5f);
        float w = 0.99f * ema_w[i] + 0.01f * dwacc[i];
        o_emaw[i]  = w;
        o_embed[i] = w / cs;
    }
    if (blockIdx.x == 0 && t == 0) {
        o_loss[0] = 0.25f * scal[0] / (float)QELEMS;
        o_perp[0] = expf(-r2[0]);
    }
}

extern "C" void kernel_launch(void* const* d_in, const int* in_sizes, int n_in,
                              void* d_out, int out_size, void* d_ws, size_t ws_size,
                              hipStream_t stream) {
    const float* in     = (const float*)d_in[0];
    const float* embed  = (const float*)d_in[1];
    const float* ema_cs = (const float*)d_in[2];
    const float* ema_w  = (const float*)d_in[3];
    float* out = (float*)d_out;
    float* ws  = (float*)d_ws;

    int*   counts_i = (int*)ws;              // 1024
    float* scal     = ws + 1024;             // 3 + wcount at 1027
    int*   wcount   = (int*)ws + 1027;
    int*   cursor   = (int*)ws + 1028;       // 1024
    float* dwacc    = ws + 2052;             // 65536 (worklist alias)
    int*   wlist    = (int*)ws + 2052;
    float* enorm    = ws + 67588;            // 1024
    _Float16* epk   = (_Float16*)(ws + 68612);   // 131072 halves (argmin phase)
    int*   keys     = (int*)ws + 68612;      // tail phase, aliases epk
    const bool use_flat = ws_size >= WS_NEED_FLAT;
    float* flat_x   = use_flat ? (ws + WS_FLAT_OFF) : (float*)0;
    float* o_idx    = out + QELEMS + 2;

    vq_epack_kernel<<<32, 256, 0, stream>>>(embed, epk, enorm, (float4*)ws);
    vq_argmin_mfma<<<512, 512, 0, stream>>>(in, embed, enorm, epk, out, o_idx,
                                            counts_i, scal, flat_x, wlist, wcount);
    vq_refine_kernel<<<256, 256, 0, stream>>>(embed, in, flat_x, o_idx, out,
                                              counts_i, scal, wlist, wcount);
    vq_scatter_kernel<<<256, 256, 0, stream>>>(o_idx, counts_i, cursor, keys);
    if (use_flat)
        vq_dw_kernel<<<1024, 256, 0, stream>>>(flat_x, keys, dwacc);
    else
        vq_dw_nchw_kernel<<<1024, 256, 0, stream>>>(in, keys, dwacc);
    vq_fin_kernel<<<32, 256, 0, stream>>>(ema_cs, ema_w, counts_i, dwacc, scal, out);
}

// Round 11
// 214.412 us; speedup vs baseline: 8.3416x; 1.0165x over previous
//
#include <hip/hip_runtime.h>
#include <math.h>

#define KCODES 1024
#define DIM 64
#define NTOT 131072          // 32*64*64 rows
#define QELEMS 8388608       // 32*64*64*64
#define TAU 1e-3f            // contested-margin threshold (>> fp16-split error bound)
#define WCAP 65536           // worklist capacity (aliases dwacc region)

typedef _Float16 half8 __attribute__((ext_vector_type(8)));
typedef float floatx4 __attribute__((ext_vector_type(4)));
typedef float floatx16 __attribute__((ext_vector_type(16)));

// ws layout (4B units):
//   0      counts_i [1024] int     (zeroed by epack)
//   1024   scal [3]: sumsq,nsum,ent; [1027] wcount int (zeroed by epack)
//   1028   cursor [1024] int       (zeroed by epack)
//   2052   dwacc [65536] float     (zeroed by epack; aliases refine worklist, re-zeroed)
//   67588  enorm [1024] float      (holds -0.5*||e||^2)
//   68612  epk [65536 floats = 131072 halves]   (argmin phase)
//   68612  keys [131072] int                    (tail phase, aliases epk)
//   199684 flat_x [8388608] float  (optional)
#define WS_ZERO_FLOATS 67588   // = 16897 float4 exactly
#define WS_FLAT_OFF 199684
#define WS_NEED_FLAT ((size_t)(WS_FLAT_OFF + QELEMS) * 4)

#define XS_STRIDE 260          // float4-aligned LDS row stride (pad 4)

// Pack embed into 32x32x16 MFMA A-fragment layout (fp16 split), compute
// enorm[k] = -0.5*||e_k||^2 (LDS reduction), AND zero the ws accumulator
// region (replaces the hipMemsetAsync node; stream order protects readers).
__global__ __launch_bounds__(256) void vq_epack_kernel(const float* __restrict__ embed,
                                                       _Float16* __restrict__ epk,
                                                       float* __restrict__ enorm,
                                                       float4* __restrict__ wsz) {
    __shared__ float sp[256];
    const int tid  = threadIdx.x;
    const int ct   = blockIdx.x;                 // 0..31
    const int gtid = ct * 256 + tid;             // 0..8191
    for (int i = gtid; i < WS_ZERO_FLOATS / 4; i += 8192)
        wsz[i] = float4{0.f, 0.f, 0.f, 0.f};

    const int kc   = (tid >> 6) & 3;
    const int lane = tid & 63;
    const int c    = ct * 32 + (lane & 31);
    const int d0   = kc * 16 + ((lane >> 5) << 3);
    const float* er = embed + c * 64 + d0;
    float4 f0 = *(const float4*)(er);
    float4 f1 = *(const float4*)(er + 4);
    float va[8] = {f0.x, f0.y, f0.z, f0.w, f1.x, f1.y, f1.z, f1.w};
    half8 h8, l8;
    float s = 0.f;
#pragma unroll
    for (int j = 0; j < 8; ++j) {
        s += va[j] * va[j];
        _Float16 ah = (_Float16)va[j];
        h8[j] = ah;
        l8[j] = (_Float16)(va[j] - (float)ah);
    }
    half8* o = (half8*)epk;
    int base = ct * 512 + kc * 64 + lane;
    o[base]       = h8;
    o[base + 256] = l8;
    sp[tid] = s;
    __syncthreads();
    if (tid < 32) {
        float tsum = 0.f;
#pragma unroll
        for (int k = 0; k < 8; ++k) tsum += sp[tid + k * 32];
        enorm[ct * 32 + tid] = -0.5f * tsum;
    }
}

// MFMA argmin, 32x32x16 tiles: 512 blocks x 512 threads; wave owns 32 pixels.
// Top-2 tracking uses two independent even/odd chains (halved dependency
// depth; exact merge at end — any tie flips land in the refine worklist).
__global__ __launch_bounds__(512, 4) void vq_argmin_mfma(
    const float* __restrict__ in,        // [32][64][64][64] NCHW
    const float* __restrict__ embed,
    const float* __restrict__ enorm,     // -0.5*||e||^2
    const _Float16* __restrict__ epk,
    float* __restrict__ out_quant,
    float* __restrict__ out_idx,
    int*   __restrict__ counts_i,
    float* __restrict__ sumsq,
    float* __restrict__ flat_x,          // or nullptr
    int*   __restrict__ wlist,
    int*   __restrict__ wcount)
{
    __shared__ float xs_lds[64 * XS_STRIDE];   // 66.56 KB  x-tile [d][row]
    __shared__ float en_s[KCODES];       // 4 KB  (-0.5*||e||^2)
    __shared__ int   hist[KCODES];       // 4 KB
    __shared__ int   widx[256];          // 1 KB
    __shared__ float wv1[256];           // 1 KB
    __shared__ float xn_s[256];          // 1 KB
    __shared__ float rsum[512];          // 2 KB

    const int t    = threadIdx.x;
    const int blk  = blockIdx.x;         // 0..511 ; block = rows [blk*256, +256)
    const int lane = t & 63;
    const int w    = t >> 6;
    const int hl   = lane >> 5;          // 0/1 half-lane group

    for (int i = t; i < KCODES; i += 512) { en_s[i] = enorm[i]; hist[i] = 0; }

    // phase 1: in -> LDS stage, float4 coalesced. Wave w handles dims
    // [w*8, +8); lane = 4-row group (rows lane*4..+3). Blocks never cross an
    // image boundary (4096 rows/image, 256 rows/block).
    const int rloc = t & 255;
    const int dhl  = t >> 8;             // 0/1 -> dims [dhl*32, +32) (phase 5)
    const int row0 = (blk << 8) + rloc;
    const int b0 = row0 >> 12, rem0 = row0 & 4095;
    {
        const int prow = (blk << 8) + (lane << 2);
        const int pb   = prow >> 12, prem = prow & 4095;
        const float* pbase = in + pb * 262144 + prem;
#pragma unroll
        for (int j = 0; j < 8; ++j) {
            float4 v = *(const float4*)(pbase + (w * 8 + j) * 4096);
            *(float4*)&xs_lds[(w * 8 + j) * XS_STRIDE + (lane << 2)] = v;
        }
    }
    __syncthreads();   // xs_lds / en_s / hist ready

    // phase 2a: B-frags from LDS + xnorm. B[k][n]: n = lane&31, k = hl*8+j.
    // Lanes l and l+32 together cover all 64 dims of pixel rowl exactly once.
    half8 xh[4], xl[4];
    float xn = 0.f;
    {
        int rowl = (w << 5) + (lane & 31);            // block-local row
#pragma unroll
        for (int kc = 0; kc < 4; ++kc) {
#pragma unroll
            for (int j = 0; j < 8; ++j) {
                float xv = xs_lds[(kc * 16 + (hl << 3) + j) * XS_STRIDE + rowl];
                xn += xv * xv;
                _Float16 hv = (_Float16)xv;
                xh[kc][j] = hv;
                xl[kc][j] = (_Float16)(xv - (float)hv);
            }
        }
        xn += __shfl_xor(xn, 32, 64);                 // full 64-dim norm
    }

    // phase 2b: flat_x dump, full-line coalesced (1 KB contiguous per instr).
    // No barrier after: stores drain under the tile loop.
    if (flat_x) {
        const int ch   = lane & 15;
        const int rsub = lane >> 4;
#pragma unroll
        for (int i = 0; i < 8; ++i) {
            int rowl = (w << 5) + (i << 2) + rsub;
            float4 v;
            v.x = xs_lds[(ch * 4 + 0) * XS_STRIDE + rowl];
            v.y = xs_lds[(ch * 4 + 1) * XS_STRIDE + rowl];
            v.z = xs_lds[(ch * 4 + 2) * XS_STRIDE + rowl];
            v.w = xs_lds[(ch * 4 + 3) * XS_STRIDE + rowl];
            *(float4*)(flat_x + (((size_t)((blk << 8) + rowl)) << 6) + (ch << 2)) = v;
        }
    }

    // phase 3: stream 32 code tiles; even/odd independent top-2 chains
    float m1a = -3.4e38f, m2a = -3.4e38f;
    float m1b = -3.4e38f, m2b = -3.4e38f;
    int   ipa = 0, ipb = 0;              // packed per-lane id: ct*16 + r

    const half8* epk8 = (const half8*)epk;
    for (int ct = 0; ct < 32; ++ct) {
        const int abase = ct * 512 + lane;
        half8 ah0 = epk8[abase];
        half8 ah1 = epk8[abase + 64];
        half8 ah2 = epk8[abase + 128];
        half8 ah3 = epk8[abase + 192];
        half8 al0 = epk8[abase + 256];
        half8 al1 = epk8[abase + 320];
        half8 al2 = epk8[abase + 384];
        half8 al3 = epk8[abase + 448];
        // C-seed: acc[g*4+i] = en_s[ct*32 + 4*hl + 8*g + i]
        const float* eb = &en_s[ct * 32 + (hl << 2)];
        floatx4 e0 = *(const floatx4*)(eb);
        floatx4 e1 = *(const floatx4*)(eb + 8);
        floatx4 e2 = *(const floatx4*)(eb + 16);
        floatx4 e3 = *(const floatx4*)(eb + 24);
        floatx16 acc;
#pragma unroll
        for (int i = 0; i < 4; ++i) {
            acc[i]      = e0[i];
            acc[4 + i]  = e1[i];
            acc[8 + i]  = e2[i];
            acc[12 + i] = e3[i];
        }
        acc = __builtin_amdgcn_mfma_f32_32x32x16_f16(ah0, xh[0], acc, 0, 0, 0);
        acc = __builtin_amdgcn_mfma_f32_32x32x16_f16(ah1, xh[1], acc, 0, 0, 0);
        acc = __builtin_amdgcn_mfma_f32_32x32x16_f16(ah2, xh[2], acc, 0, 0, 0);
        acc = __builtin_amdgcn_mfma_f32_32x32x16_f16(ah3, xh[3], acc, 0, 0, 0);
        acc = __builtin_amdgcn_mfma_f32_32x32x16_f16(al0, xh[0], acc, 0, 0, 0);
        acc = __builtin_amdgcn_mfma_f32_32x32x16_f16(al1, xh[1], acc, 0, 0, 0);
        acc = __builtin_amdgcn_mfma_f32_32x32x16_f16(al2, xh[2], acc, 0, 0, 0);
        acc = __builtin_amdgcn_mfma_f32_32x32x16_f16(al3, xh[3], acc, 0, 0, 0);
        acc = __builtin_amdgcn_mfma_f32_32x32x16_f16(ah0, xl[0], acc, 0, 0, 0);
        acc = __builtin_amdgcn_mfma_f32_32x32x16_f16(ah1, xl[1], acc, 0, 0, 0);
        acc = __builtin_amdgcn_mfma_f32_32x32x16_f16(ah2, xl[2], acc, 0, 0, 0);
        acc = __builtin_amdgcn_mfma_f32_32x32x16_f16(ah3, xl[3], acc, 0, 0, 0);
        const int kb = ct << 4;
#pragma unroll
        for (int r = 0; r < 16; r += 2) {
            float a = acc[r];
            m2a = __builtin_amdgcn_fmed3f(a, m1a, m2a);   // new 2nd (m1a>=m2a)
            if (a > m1a) ipa = kb + r;
            m1a = fmaxf(m1a, a);
            float b = acc[r + 1];
            m2b = __builtin_amdgcn_fmed3f(b, m1b, m2b);
            if (b > m1b) ipb = kb + r + 1;
            m1b = fmaxf(m1b, b);
        }
    }

    // phase 4: merge even/odd chains (exact), then cross-half-lane merge
    {
        int rra = ipa & 15, cta = ipa >> 4;
        int ca = cta * 32 + (rra & 3) + ((rra >> 2) << 3) + (hl << 2);
        int rrb = ipb & 15, ctb = ipb >> 4;
        int cb = ctb * 32 + (rrb & 3) + ((rrb >> 2) << 3) + (hl << 2);
        float a1v, a2v; int ai;
        if (m1b > m1a || (m1b == m1a && cb < ca)) {
            a1v = m1b; ai = cb; a2v = fmaxf(m2b, m1a);
        } else {
            a1v = m1a; ai = ca; a2v = fmaxf(m2a, m1b);
        }
        float o1 = __shfl_xor(a1v, 32, 64);
        int   oi = __shfl_xor(ai, 32, 64);
        float o2 = __shfl_xor(a2v, 32, 64);
        if (o1 > a1v || (o1 == a1v && oi < ai)) {
            a2v = fmaxf(a1v, o2); a1v = o1; ai = oi;
        } else {
            a2v = fmaxf(a2v, o1);
        }
        if (lane < 32) {
            int pl  = (w << 5) + lane;
            int row = (blk << 8) + pl;
            widx[pl] = ai;
            wv1[pl]  = -2.0f * a1v;                   // = dv_min
            xn_s[pl] = xn;
            out_idx[row] = (float)ai;
            atomicAdd(&hist[ai], 1);
            if (2.0f * (a1v - a2v) < TAU) {           // dv2 - dv1 < TAU
                int pos = atomicAdd(wcount, 1);
                if (pos < WCAP) wlist[pos] = row;
            }
        }
    }
    __syncthreads();

    // phase 5: hist flush + quant write + sumsq (dv_min + |x|^2)
    for (int i = t; i < KCODES; i += 512) {
        int v = hist[i];
        if (v) atomicAdd(&counts_i[i], v);
    }
    {
        int k = widx[rloc];
        const float4* eq = (const float4*)(embed + (k << 6) + (dhl << 5));
        float* ob = out_quant + b0 * 262144 + (dhl << 5) * 4096 + rem0;
#pragma unroll
        for (int d4 = 0; d4 < 8; ++d4) {
            float4 e4v = eq[d4];
            ob[(d4 * 4 + 0) * 4096] = e4v.x;
            ob[(d4 * 4 + 1) * 4096] = e4v.y;
            ob[(d4 * 4 + 2) * 4096] = e4v.z;
            ob[(d4 * 4 + 3) * 4096] = e4v.w;
        }
        rsum[t] = (t < 256) ? (wv1[t] + xn_s[t]) : 0.f;
    }
    __syncthreads();
    for (int s = 256; s > 0; s >>= 1) {
        if (t < s) rsum[t] += rsum[t + s];
        __syncthreads();
    }
    if (t == 0) atomicAdd(sumsq, rsum[0]);
}

// Refine of contested pixels, fp32 direct distances (error ~1e-5 << TAU=1e-3).
// Patches idx/quant/counts/loss; restores wlist=0 (dwacc alias).
__global__ __launch_bounds__(256) void vq_refine_kernel(
    const float* __restrict__ embed,
    const float* __restrict__ in,
    const float* __restrict__ flat_x,    // may be null
    float* __restrict__ out_idx,
    float* __restrict__ out_quant,
    int*   __restrict__ counts_i,
    float* __restrict__ scal,            // [0]=sumsq
    int*   __restrict__ wlist,
    const int* __restrict__ wcount)
{
    const int lane = threadIdx.x & 63;
    const int gw   = (blockIdx.x << 2) + (threadIdx.x >> 6);
    const int nw   = gridDim.x << 2;
    int count = *wcount;
    if (count > WCAP) count = WCAP;

    for (int e = gw; e < count; e += nw) {
        int r = wlist[e];
        int b = r >> 12, rem = r & 4095;
        float4 xr[16];
        if (flat_x) {
            const float4* xs4 = (const float4*)(flat_x + ((size_t)r << 6));
#pragma unroll
            for (int qq = 0; qq < 16; ++qq) xr[qq] = xs4[qq];
        } else {
#pragma unroll
            for (int qq = 0; qq < 16; ++qq) {
                xr[qq].x = in[b * 262144 + (qq * 4 + 0) * 4096 + rem];
                xr[qq].y = in[b * 262144 + (qq * 4 + 1) * 4096 + rem];
                xr[qq].z = in[b * 262144 + (qq * 4 + 2) * 4096 + rem];
                xr[qq].w = in[b * 262144 + (qq * 4 + 3) * 4096 + rem];
            }
        }
        float bv = 3.4e38f;
        int   bi = 0;
        for (int j = 0; j < 16; ++j) {
            int c = (j << 6) + lane;
            const float4* er = (const float4*)(embed + (c << 6));
            float acc = 0.f;
#pragma unroll
            for (int qq = 0; qq < 16; ++qq) {
                float4 ev = er[qq];
                float d0 = xr[qq].x - ev.x;
                float d1 = xr[qq].y - ev.y;
                float d2 = xr[qq].z - ev.z;
                float d3 = xr[qq].w - ev.w;
                acc += d0 * d0 + d1 * d1 + d2 * d2 + d3 * d3;
            }
            if (acc < bv) { bv = acc; bi = c; }
        }
#pragma unroll
        for (int off = 1; off < 64; off <<= 1) {
            float ov = __shfl_xor(bv, off, 64);
            int   oi = __shfl_xor(bi, off, 64);
            if (ov < bv || (ov == bv && oi < bi)) { bv = ov; bi = oi; }
        }
        int oldi = (int)out_idx[r];
        if (bi != oldi) {
            float xd = flat_x ? flat_x[((size_t)r << 6) + lane]
                              : in[b * 262144 + lane * 4096 + rem];
            float en_ = embed[(bi << 6) + lane];
            float eo_ = embed[(oldi << 6) + lane];
            out_quant[b * 262144 + lane * 4096 + rem] = en_;
            float dl = (en_ - xd) * (en_ - xd) - (eo_ - xd) * (eo_ - xd);
#pragma unroll
            for (int off = 1; off < 64; off <<= 1) dl += __shfl_xor(dl, off, 64);
            if (lane == 0) {
                out_idx[r] = (float)bi;
                atomicAdd(&scal[0], dl);
                atomicSub(&counts_i[oldi], 1);
                atomicAdd(&counts_i[bi], 1);
            }
        }
        if (lane == 0) wlist[e] = 0;   // restore dwacc zero
    }
}

// ---- tail ----
__global__ __launch_bounds__(256) void vq_scatter_kernel(
    const float* __restrict__ idxf,
    const int*   __restrict__ counts_i,
    int* __restrict__ cursor,
    int* __restrict__ keys)
{
    __shared__ int lstarts[KCODES];
    __shared__ int lh[KCODES];
    __shared__ int part[256];
    const int t   = threadIdx.x;
    const int blk = blockIdx.x;

    int4 c4 = *(const int4*)(counts_i + (t << 2));
    part[t] = c4.x + c4.y + c4.z + c4.w;
    {
        int tb = t << 2;
        lh[tb] = 0; lh[tb + 1] = 0; lh[tb + 2] = 0; lh[tb + 3] = 0;
    }
    __syncthreads();
    for (int off = 1; off < 256; off <<= 1) {
        int v   = part[t];
        int add = (t >= off) ? part[t - off] : 0;
        __syncthreads();
        part[t] = v + add;
        __syncthreads();
    }
    {
        int base = (t == 0) ? 0 : part[t - 1];
        int tb = t << 2;
        lstarts[tb]     = base;
        lstarts[tb + 1] = base + c4.x;
        lstarts[tb + 2] = base + c4.x + c4.y;
        lstarts[tb + 3] = base + c4.x + c4.y + c4.z;
    }
    __syncthreads();

    const int i0 = (blk << 9) + t;
    const int i1 = i0 + 256;
    int code0 = (int)idxf[i0];
    int rank0 = atomicAdd(&lh[code0], 1);
    int code1 = (int)idxf[i1];
    int rank1 = atomicAdd(&lh[code1], 1);
    __syncthreads();
    for (int k = t; k < KCODES; k += 256) {
        int cnt = lh[k];
        if (cnt) lh[k] = lstarts[k] + atomicAdd(&cursor[k], cnt);
    }
    __syncthreads();
    keys[lh[code0] + rank0] = (code0 << 17) | i0;
    keys[lh[code1] + rank1] = (code1 << 17) | i1;
}

// dw segment-sum over sorted keys: 2048 blocks (8192 waves = 8/SIMD), 16
// keys/wave, one-iter x-prefetch. Run splits across chunk boundaries are
// exact (flush-at-end + atomic adds).
__global__ __launch_bounds__(256) void vq_dw_kernel(
    const float* __restrict__ flat_x,
    const int*   __restrict__ keys,
    float* __restrict__ dwacc)
{
    const int t   = threadIdx.x;
    const int blk = blockIdx.x;
    const int wv  = t >> 6, d = t & 63;
    const int base = (blk << 6) + (wv << 4);   // 16 keys per wave

    int key   = keys[base];
    int c_cur = key >> 17;
    int r     = key & 0x1FFFF;
    float x   = flat_x[((size_t)r << 6) + d];
    float acc = 0.f;
#pragma unroll 4
    for (int m = 0; m < 16; ++m) {
        int nkey = (m < 15) ? keys[base + m + 1] : -1;
        int c_n  = nkey >> 17;
        int r_n  = nkey & 0x1FFFF;
        float x_n = (m < 15) ? flat_x[((size_t)r_n << 6) + d] : 0.f;
        acc += x;
        if (c_n != c_cur) {
            atomicAdd(&dwacc[(c_cur << 6) + d], acc);
            acc = 0.f;
            c_cur = c_n;
        }
        x = x_n;
        r = r_n;
    }
}

__global__ __launch_bounds__(256) void vq_dw_nchw_kernel(
    const float* __restrict__ in,
    const int*   __restrict__ keys,
    float* __restrict__ dwacc)
{
    const int t   = threadIdx.x;
    const int blk = blockIdx.x;
    const int wv  = t >> 6, d = t & 63;
    const int base = (blk << 6) + (wv << 4);

    int key   = keys[base];
    int c_cur = key >> 17;
    int r     = key & 0x1FFFF;
    float acc = 0.f;
    for (int m = 0; m < 16; ++m) {
        int b = r >> 12, rem = r & 4095;
        float x = in[b * 262144 + d * 4096 + rem];
        int nkey = (m < 15) ? keys[base + m + 1] : -1;
        int c_n  = nkey >> 17;
        int r_n  = nkey & 0x1FFFF;
        acc += x;
        if (c_n != c_cur) {
            atomicAdd(&dwacc[(c_cur << 6) + d], acc);
            acc = 0.f;
            c_cur = c_n;
        }
        r = r_n;
    }
}

// Fused finalize: every block redundantly computes n = sum(ncs); block 0 also
// does entropy, o_ncs, loss, perplexity.
__global__ __launch_bounds__(256) void vq_fin_kernel(
    const float* __restrict__ ema_cs,
    const float* __restrict__ ema_w,
    const int*   __restrict__ counts_i,
    const float* __restrict__ dwacc,
    const float* __restrict__ scal,
    float* __restrict__ out)
{
    __shared__ float r1[256], r2[256];
    const int t = threadIdx.x;
    float* o_loss  = out + QELEMS;
    float* o_perp  = out + QELEMS + 1;
    float* o_ncs   = out + QELEMS + 2 + NTOT;
    float* o_emaw  = o_ncs + KCODES;
    float* o_embed = o_emaw + KCODES * DIM;

    int4   ci = *(const int4*)(counts_i + (t << 2));
    float4 ec = *(const float4*)(ema_cs + (t << 2));
    float ncs0 = 0.99f * ec.x + 0.01f * (float)ci.x;
    float ncs1 = 0.99f * ec.y + 0.01f * (float)ci.y;
    float ncs2 = 0.99f * ec.z + 0.01f * (float)ci.z;
    float ncs3 = 0.99f * ec.w + 0.01f * (float)ci.w;
    r1[t] = ncs0 + ncs1 + ncs2 + ncs3;
    {
        float p0 = (float)ci.x / (float)NTOT, p1 = (float)ci.y / (float)NTOT;
        float p2 = (float)ci.z / (float)NTOT, p3 = (float)ci.w / (float)NTOT;
        r2[t] = p0 * logf(p0 + 1e-10f) + p1 * logf(p1 + 1e-10f)
              + p2 * logf(p2 + 1e-10f) + p3 * logf(p3 + 1e-10f);
    }
    if (blockIdx.x == 0) {
        float4* on4 = (float4*)(o_ncs + (t << 2));
        *on4 = float4{ncs0, ncs1, ncs2, ncs3};
    }
    __syncthreads();
    for (int s = 128; s > 0; s >>= 1) {
        if (t < s) { r1[t] += r1[t + s]; r2[t] += r2[t + s]; }
        __syncthreads();
    }
    float n = r1[0];
    float denom = n + (float)KCODES * 1e-5f;
#pragma unroll
    for (int u = 0; u < 8; ++u) {
        int i = (blockIdx.x << 11) + (u << 8) + t;
        int k = i >> 6;
        float c   = (float)counts_i[k];
        float ncs = 0.99f * ema_cs[k] + 0.01f * c;
        float cs  = (ncs + 1e-5f) / denom * n;
        cs = fmaxf(cs, 1e-5f);
        float w = 0.99f * ema_w[i] + 0.01f * dwacc[i];
        o_emaw[i]  = w;
        o_embed[i] = w / cs;
    }
    if (blockIdx.x == 0 && t == 0) {
        o_loss[0] = 0.25f * scal[0] / (float)QELEMS;
        o_perp[0] = expf(-r2[0]);
    }
}

extern "C" void kernel_launch(void* const* d_in, const int* in_sizes, int n_in,
                              void* d_out, int out_size, void* d_ws, size_t ws_size,
                              hipStream_t stream) {
    const float* in     = (const float*)d_in[0];
    const float* embed  = (const float*)d_in[1];
    const float* ema_cs = (const float*)d_in[2];
    const float* ema_w  = (const float*)d_in[3];
    float* out = (float*)d_out;
    float* ws  = (float*)d_ws;

    int*   counts_i = (int*)ws;              // 1024
    float* scal     = ws + 1024;             // 3 + wcount at 1027
    int*   wcount   = (int*)ws + 1027;
    int*   cursor   = (int*)ws + 1028;       // 1024
    float* dwacc    = ws + 2052;             // 65536 (worklist alias)
    int*   wlist    = (int*)ws + 2052;
    float* enorm    = ws + 67588;            // 1024
    _Float16* epk   = (_Float16*)(ws + 68612);   // 131072 halves (argmin phase)
    int*   keys     = (int*)ws + 68612;      // tail phase, aliases epk
    const bool use_flat = ws_size >= WS_NEED_FLAT;
    float* flat_x   = use_flat ? (ws + WS_FLAT_OFF) : (float*)0;
    float* o_idx    = out + QELEMS + 2;

    vq_epack_kernel<<<32, 256, 0, stream>>>(embed, epk, enorm, (float4*)ws);
    vq_argmin_mfma<<<512, 512, 0, stream>>>(in, embed, enorm, epk, out, o_idx,
                                            counts_i, scal, flat_x, wlist, wcount);
    vq_refine_kernel<<<256, 256, 0, stream>>>(embed, in, flat_x, o_idx, out,
                                              counts_i, scal, wlist, wcount);
    vq_scatter_kernel<<<256, 256, 0, stream>>>(o_idx, counts_i, cursor, keys);
    if (use_flat)
        vq_dw_kernel<<<2048, 256, 0, stream>>>(flat_x, keys, dwacc);
    else
        vq_dw_nchw_kernel<<<2048, 256, 0, stream>>>(in, keys, dwacc);
    vq_fin_kernel<<<32, 256, 0, stream>>>(ema_cs, ema_w, counts_i, dwacc, scal, out);
}